// Round 7
// baseline (136.978 us; speedup 1.0000x reference)
//
#include <hip/hip_runtime.h>

typedef float    v4f    __attribute__((ext_vector_type(4)));
typedef short    bf16x8 __attribute__((ext_vector_type(8)));
typedef unsigned u32x4  __attribute__((ext_vector_type(4)));
typedef unsigned short u16;

__constant__ unsigned char c_pair[28] = {
  1,2,3,4,5,6,7, 10,11,12,13,14,15, 19,20,21,22,23, 28,29,30,31, 37,38,39, 46,47, 55
};

static __device__ __forceinline__ unsigned asu(float f){ union{float f;unsigned u;}v; v.f=f; return v.u; }
static __device__ __forceinline__ float lo2f(unsigned d){ union{unsigned u;float f;}v; v.u = d<<16; return v.f; }
static __device__ __forceinline__ float hi2f(unsigned d){ union{unsigned u;float f;}v; v.u = d & 0xffff0000u; return v.f; }
static __device__ __forceinline__ unsigned pkt(float lo, float hi){
  return __builtin_amdgcn_perm(asu(hi), asu(lo), 0x07060302u);
}

// ---------------- ws image layout ----------------
#define WS_W1AB 0
#define WS_W1G  65536
#define WS_W2   98304
#define WS_GP   114688
#define WS_NEED 4308992

// ================= prep kernels =================
__global__ __launch_bounds__(1024)
void prep_weights(const float* __restrict__ W1, const float* __restrict__ W2, char* __restrict__ ws)
{
  const int idx = blockIdx.x * 1024 + threadIdx.x;   // 28 blocks * 1024 = 28672
  if (idx < 16384) {
    const int c = idx >> 6, kp = idx & 63;
    const int part = c >> 7, cc = c & 127;
    const float a  = W1[(size_t)(part * 128 + 2 * kp) * 128 + cc];
    const float b_ = W1[(size_t)(part * 128 + 2 * kp + 1) * 128 + cc];
    *(unsigned*)(ws + WS_W1AB + (size_t)c * 256 + ((kp * 4) ^ ((c & 7) << 4))) = pkt(a, b_);
  } else if (idx < 24576) {
    const int j = idx - 16384, c = j >> 6, kp = j & 63;
    const float a  = W1[(size_t)(256 + 2 * kp) * 128 + c];
    const float b_ = W1[(size_t)(256 + 2 * kp + 1) * 128 + c];
    *(unsigned*)(ws + WS_W1G + (size_t)c * 256 + ((kp * 4) ^ ((c & 7) << 4))) = pkt(a, b_);
  } else if (idx < 28672) {
    const int j = idx - 24576, c = j >> 6, kp = j & 63;
    const float a  = W2[(size_t)(2 * kp) * 64 + c];
    const float b_ = W2[(size_t)(2 * kp + 1) * 64 + c];
    *(unsigned*)(ws + WS_W2 + (size_t)c * 256 + ((kp * 4) ^ ((c & 7) << 4))) = pkt(a, b_);
  }
}

__global__ __launch_bounds__(256)
void prep_gp(const float* __restrict__ glob, const float* __restrict__ b1, char* __restrict__ ws)
{
  __shared__ __align__(16) char sm[65536];   // [0,32K) glob tile bf16 swz; [32K,64K) W1gT
  const int tid = threadIdx.x;
  const int bb0 = blockIdx.x * 128;          // 128 blocks x 128 batches
  for (int i = tid; i < 2048; i += 256) {
    const u32x4 v = *(const u32x4*)(ws + WS_W1G + i * 16);
    *(u32x4*)(sm + 32768 + i * 16) = v;
  }
  for (int i = tid; i < 4096; i += 256) {
    const int r = i >> 5, q = i & 31;
    const float4 f = *(const float4*)(glob + (size_t)(bb0 + r) * 128 + q * 4);
    int2 w; w.x = (int)pkt(f.x, f.y); w.y = (int)pkt(f.z, f.w);
    *(int2*)(sm + r * 256 + ((q * 8) ^ ((r & 7) << 4))) = w;
  }
  __syncthreads();
  const int wave = tid >> 6, lane = tid & 63, lrow = lane & 15, lko = (lane >> 4) * 8;
  float b1c[8];
#pragma unroll
  for (int nt = 0; nt < 8; ++nt) b1c[nt] = b1[nt * 16 + lrow];
  const v4f vzero = {0.f, 0.f, 0.f, 0.f};
  v4f acc[2][8];
#pragma unroll
  for (int mt = 0; mt < 2; ++mt)
#pragma unroll
    for (int nt = 0; nt < 8; ++nt) acc[mt][nt] = vzero;
#pragma unroll
  for (int ks = 0; ks < 4; ++ks) {
    const int kb = (ks * 32 + lko) * 2;
    bf16x8 af[2];
#pragma unroll
    for (int mt = 0; mt < 2; ++mt) {
      const int r = wave * 32 + mt * 16 + lrow;
      af[mt] = *(const bf16x8*)(sm + r * 256 + (kb ^ ((r & 7) << 4)));
    }
#pragma unroll
    for (int nt = 0; nt < 8; ++nt) {
      const int c = nt * 16 + lrow;
      const bf16x8 bfr = *(const bf16x8*)(sm + 32768 + c * 256 + (kb ^ ((c & 7) << 4)));
#pragma unroll
      for (int mt = 0; mt < 2; ++mt)
        acc[mt][nt] = __builtin_amdgcn_mfma_f32_16x16x32_bf16(af[mt], bfr, acc[mt][nt], 0, 0, 0);
    }
  }
#pragma unroll
  for (int mt = 0; mt < 2; ++mt)
#pragma unroll
    for (int nt = 0; nt < 8; ++nt) {
      const int c = nt * 16 + lrow;
#pragma unroll
      for (int rg = 0; rg < 4; ++rg) {
        const int m = wave * 32 + mt * 16 + (lane >> 4) * 4 + rg;
        const int batch = bb0 + m;
        const int g = batch >> 4, q = m & 15;
        *(u16*)(ws + WS_GP + (size_t)g * 4096 + q * 256 + ((c * 2) ^ ((q & 7) << 4))) =
            (u16)(asu(acc[mt][nt][rg] + b1c[nt]) >> 16);
      }
    }
}

// ================= main kernel =================
// 256 blocks (1/CU) x 1024 threads (16 waves); each block: 64 batches = 4 tiles of 16.
// Phase-1 A-operand comes straight from GLOBAL (f32 -> bf16 pack in registers):
// no node LDS buffer, no cross-barrier register arrays -> fits the 64-VGPR cap
// without scratch spill (R4-R6 spilled ~140 MB/dispatch via cross-barrier af/acc).
#define M_OFF_W   0        // 65536: W1abT rows 0..255
#define M_OFF_W2  65536    // 16384: W2T rows 0..63
#define M_OFF_PA  81920    // 32768: Pa [128][256B]
#define M_OFF_PB  114688   // 32768: Pb [128][256B]
#define M_OFF_GP  147456   // 4096 : gp tile [16][256B]
#define M_OFF_V   151552   // 512  : b2 f32[64] | W3 f32[64]
#define M_SMEM    152064

__global__ __attribute__((amdgpu_flat_work_group_size(1024, 1024), amdgpu_waves_per_eu(4, 4)))
void docking_main(const float* __restrict__ node, const int* __restrict__ dmask,
                  const float* __restrict__ b2, const float* __restrict__ W3,
                  const float* __restrict__ b3,
                  const char* __restrict__ ws, float* __restrict__ outp)
{
  __shared__ __align__(16) char smem[M_SMEM];
  const int tid = threadIdx.x;
  const int wave = tid >> 6, lane = tid & 63, lrow = lane & 15, lko = (lane >> 4) * 8;
  const int wm = wave >> 2, wn = wave & 3;
  const int bbBlk = blockIdx.x * 64;
  const float bias3 = *b3;
  const v4f vzero = {0.f, 0.f, 0.f, 0.f};

  // ---- stage weights once (pure 16B copies of pre-swizzled images) ----
  for (int i = tid; i < 4096; i += 1024) {
    const u32x4 v = *(const u32x4*)(ws + WS_W1AB + i * 16);
    *(u32x4*)(smem + M_OFF_W + i * 16) = v;
  }
  {
    const u32x4 v = *(const u32x4*)(ws + WS_W2 + tid * 16);
    *(u32x4*)(smem + M_OFF_W2 + tid * 16) = v;
  }
  if (tid < 64)       ((float*)(smem + M_OFF_V))[tid] = b2[tid];
  else if (tid < 128) ((float*)(smem + M_OFF_V))[tid] = W3[tid - 64];
  __syncthreads();

#pragma unroll 1
  for (int bt = 0; bt < 4; ++bt) {
    const int bb0 = bbBlk + bt * 16;

    // gp tile copy (global->LDS, 16B lanes); visible after barrier (3)
    if (tid < 256) {
      const u32x4 v = *(const u32x4*)(ws + WS_GP + ((size_t)(bb0 >> 4)) * 4096 + tid * 16);
      *(u32x4*)(smem + M_OFF_GP + tid * 16) = v;
    }

    // ---- phase 1: proj GEMM; A from global, B from LDS, out -> Pa/Pb ----
    // this wave's A rows: wm*32 + mt*16 + lrow; k-window: ks*32 + lko
    const float* arow0 = node + ((size_t)bb0 * 8 + wm * 32 + lrow) * 128 + lko;
    const int pbase = (wn >= 2) ? M_OFF_PB : M_OFF_PA;
    const int rgb = (lane >> 4) * 4;

    auto loadAF = [&](bf16x8* dst, int ks) {
#pragma unroll
      for (int mt = 0; mt < 2; ++mt) {
        const float* s = arow0 + mt * 2048 + ks * 32;
        const float4 f0 = *(const float4*)(s);
        const float4 f1 = *(const float4*)(s + 4);
        union { u32x4 u; bf16x8 h; } cv;
        cv.u[0] = pkt(f0.x, f0.y); cv.u[1] = pkt(f0.z, f0.w);
        cv.u[2] = pkt(f1.x, f1.y); cv.u[3] = pkt(f1.z, f1.w);
        dst[mt] = cv.h;
      }
    };

#pragma unroll 1
    for (int half = 0; half < 2; ++half) {
      v4f acc[2][2];
#pragma unroll
      for (int mt = 0; mt < 2; ++mt)
#pragma unroll
        for (int nt = 0; nt < 2; ++nt) acc[mt][nt] = vzero;

      bf16x8 afc[2];
      loadAF(afc, 0);
#pragma unroll 1
      for (int ks = 0; ks < 4; ++ks) {
        bf16x8 afn[2];
        loadAF(afn, (ks < 3) ? ks + 1 : 3);      // rotate; clamp avoids OOB
        const int kb = (ks * 32 + lko) * 2;
#pragma unroll
        for (int nt = 0; nt < 2; ++nt) {
          const int c = wn * 64 + (half * 2 + nt) * 16 + lrow;
          const bf16x8 bfr = *(const bf16x8*)(smem + M_OFF_W + c * 256 + (kb ^ ((c & 7) << 4)));
#pragma unroll
          for (int mt = 0; mt < 2; ++mt)
            acc[mt][nt] = __builtin_amdgcn_mfma_f32_16x16x32_bf16(afc[mt], bfr, acc[mt][nt], 0, 0, 0);
        }
        afc[0] = afn[0]; afc[1] = afn[1];
      }
      // write this half's proj immediately (no barrier needed: Pa/Pb not read in phase 1)
#pragma unroll
      for (int nt = 0; nt < 2; ++nt) {
        const int c = (wn & 1) * 64 + (half * 2 + nt) * 16 + lrow;
#pragma unroll
        for (int mt = 0; mt < 2; ++mt)
#pragma unroll
          for (int rg = 0; rg < 4; ++rg) {
            const int m = wm * 32 + mt * 16 + rgb + rg;
            *(u16*)(smem + pbase + m * 256 + ((c * 2) ^ ((m & 7) << 4))) =
                (u16)(asu(acc[mt][nt][rg]) >> 16);
          }
      }
    }
    __syncthreads();                                   // (3) proj + gp visible

    // ---- phase 2: pair MLP (28 tiles of 16 pair-rows over 16 waves) ----
    for (int t = wave; t < 28; t += 16) {
      const int r  = t * 16 + lrow;
      const int bb = (r * 9363) >> 18;                 // r/28 for r<2340
      const int p  = r - bb * 28;
      const unsigned pr8 = c_pair[p];
      const int mi = bb * 8 + (int)(pr8 >> 3);
      const int mj = bb * 8 + (int)(pr8 & 7);

      v4f acc2[4] = {vzero, vzero, vzero, vzero};
#pragma unroll
      for (int ks = 0; ks < 4; ++ks) {
        const int kb = (ks * 32 + lko) * 2;
        const u32x4 va = *(const u32x4*)(smem + M_OFF_PA + mi * 256 + (kb ^ ((mi & 7) << 4)));
        const u32x4 vb = *(const u32x4*)(smem + M_OFF_PB + mj * 256 + (kb ^ ((mj & 7) << 4)));
        const u32x4 vg = *(const u32x4*)(smem + M_OFF_GP + bb * 256 + (kb ^ ((bb & 7) << 4)));
        u32x4 a2;
#pragma unroll
        for (int w = 0; w < 4; ++w) {
          const float lo = fmaxf(lo2f(va[w]) + lo2f(vb[w]) + lo2f(vg[w]), 0.0f);
          const float hi = fmaxf(hi2f(va[w]) + hi2f(vb[w]) + hi2f(vg[w]), 0.0f);
          a2[w] = pkt(lo, hi);
        }
        union { u32x4 u; bf16x8 h; } cv; cv.u = a2;
#pragma unroll
        for (int nt = 0; nt < 4; ++nt) {
          const int cc = nt * 16 + lrow;
          const bf16x8 w2fr = *(const bf16x8*)(smem + M_OFF_W2 + cc * 256 + (kb ^ ((cc & 7) << 4)));
          acc2[nt] = __builtin_amdgcn_mfma_f32_16x16x32_bf16(cv.h, w2fr, acc2[nt], 0, 0, 0);
        }
      }
      // epilogue: b2/W3 straight from LDS (saves 8 persistent VGPRs)
      const float* sV = (const float*)(smem + M_OFF_V);
      float part[4] = {0.f, 0.f, 0.f, 0.f};
#pragma unroll
      for (int nt = 0; nt < 4; ++nt) {
        const int n = nt * 16 + lrow;
        const float b2v = sV[n], w3v = sV[64 + n];
#pragma unroll
        for (int rg = 0; rg < 4; ++rg)
          part[rg] += fmaxf(acc2[nt][rg] + b2v, 0.0f) * w3v;
      }
#pragma unroll
      for (int mk = 1; mk < 16; mk <<= 1)
#pragma unroll
        for (int rg = 0; rg < 4; ++rg) part[rg] += __shfl_xor(part[rg], mk, 16);

      if ((lane & 15) == 0) {
        const int rb = t * 16 + (lane >> 4) * 4;
#pragma unroll
        for (int rg = 0; rg < 4; ++rg) {
          const int rr = rb + rg;
          const int b2_ = (rr * 9363) >> 18;
          const int p2  = rr - b2_ * 28;
          const size_t o = (size_t)(bb0 + b2_) * 28 + p2;
          outp[o] = dmask[o] ? (part[rg] + bias3) : -1.0e9f;
        }
      }
    }
    __syncthreads();                                   // (4) phase-2 reads done
  }
}

// ================= fallback (proven R3 fused kernel) =================
#define F_THREADS 512
#define F_NB      8
#define F_OFF_A    0
#define F_OFF_GL   16384
#define F_OFF_SB   20480
#define F_OFF_W2   53248
#define F_OFF_B1V  69632
#define F_OFF_B2V  70144
#define F_OFF_W3V  70400
#define F_SMEM     70656

__global__ __launch_bounds__(F_THREADS, 4)
void docking_fused(const float* __restrict__ node, const float* __restrict__ glob,
                   const int* __restrict__ dmask,
                   const float* __restrict__ W1, const float* __restrict__ b1,
                   const float* __restrict__ W2, const float* __restrict__ b2,
                   const float* __restrict__ W3, const float* __restrict__ b3,
                   float* __restrict__ outp)
{
  __shared__ __align__(16) char smem[F_SMEM];
  const int tid = threadIdx.x;
  const int bb0 = blockIdx.x * F_NB;
  const size_t nrow0 = (size_t)bb0 * 8;
  const float bias3 = *b3;

  if (tid < 128)      ((float*)(smem + F_OFF_B1V))[tid]       = b1[tid];
  else if (tid < 192) ((float*)(smem + F_OFF_B2V))[tid - 128] = b2[tid - 128];
  else if (tid < 256) ((float*)(smem + F_OFF_W3V))[tid - 192] = W3[tid - 192];

  for (int idx = tid; idx < 64 * 32; idx += F_THREADS) {
    const int r = idx >> 5, q = idx & 31;
    const float4 f = *(const float4*)(node + (nrow0 + (size_t)r) * 128 + q * 4);
    int2 w; w.x = (int)pkt(f.x, f.y); w.y = (int)pkt(f.z, f.w);
    *(int2*)(smem + F_OFF_A + r * 256 + ((q * 8) ^ ((r & 7) << 4))) = w;
  }
  for (int idx = tid; idx < 16 * 32; idx += F_THREADS) {
    const int r = idx >> 5, q = idx & 31;
    float4 f = make_float4(0.f, 0.f, 0.f, 0.f);
    if (r < F_NB) f = *(const float4*)(glob + (size_t)(bb0 + r) * 128 + q * 4);
    int2 w; w.x = (int)pkt(f.x, f.y); w.y = (int)pkt(f.z, f.w);
    *(int2*)(smem + F_OFF_GL + r * 256 + ((q * 8) ^ ((r & 7) << 4))) = w;
  }
  for (int idx = tid; idx < 4096; idx += F_THREADS) {
    const int cl = idx & 7, kl = (idx >> 3) & 7, ch = (idx >> 6) & 7, kh = idx >> 9;
    const int c = cl | (ch << 3), kp = kl | (kh << 3);
    const float a  = W2[(size_t)(2 * kp) * 64 + c];
    const float b_ = W2[(size_t)(2 * kp + 1) * 64 + c];
    *(unsigned*)(smem + F_OFF_W2 + c * 256 + ((kp * 4) ^ ((c & 7) << 4))) = pkt(a, b_);
  }
  auto stageB = [&](int rowOff) {
    for (int idx = tid; idx < 8192; idx += F_THREADS) {
      const int cl = idx & 7, kl = (idx >> 3) & 7, ch = (idx >> 6) & 15, kh = idx >> 10;
      const int c = cl | (ch << 3), kp = kl | (kh << 3);
      const float a  = W1[(size_t)(rowOff + 2 * kp) * 128 + c];
      const float b_ = W1[(size_t)(rowOff + 2 * kp + 1) * 128 + c];
      *(unsigned*)(smem + F_OFF_SB + c * 256 + ((kp * 4) ^ ((c & 7) << 4))) = pkt(a, b_);
    }
  };
  stageB(0);
  __syncthreads();

  const int wave = tid >> 6, lane = tid & 63;
  const int lrow = lane & 15;
  const int lko  = (lane >> 4) * 8;
  const int wmt = wave >> 1, wnh = wave & 1;
  const v4f vzero = {0.f, 0.f, 0.f, 0.f};

  bf16x8 af[4];
#pragma unroll
  for (int ks = 0; ks < 4; ++ks) {
    const int r = wmt * 16 + lrow;
    af[ks] = *(const bf16x8*)(smem + F_OFF_A + r * 256 + (((ks * 32 + lko) * 2) ^ ((r & 7) << 4)));
  }
  v4f acc_a[4] = {vzero, vzero, vzero, vzero};
#pragma unroll
  for (int ks = 0; ks < 4; ++ks) {
    const int kb = (ks * 32 + lko) * 2;
#pragma unroll
    for (int nt = 0; nt < 4; ++nt) {
      const int c = wnh * 64 + nt * 16 + lrow;
      const bf16x8 bfr = *(const bf16x8*)(smem + F_OFF_SB + c * 256 + (kb ^ ((c & 7) << 4)));
      acc_a[nt] = __builtin_amdgcn_mfma_f32_16x16x32_bf16(af[ks], bfr, acc_a[nt], 0, 0, 0);
    }
  }
  __syncthreads();
  stageB(128);
  __syncthreads();
  v4f acc_b[4] = {vzero, vzero, vzero, vzero};
#pragma unroll
  for (int ks = 0; ks < 4; ++ks) {
    const int kb = (ks * 32 + lko) * 2;
#pragma unroll
    for (int nt = 0; nt < 4; ++nt) {
      const int c = wnh * 64 + nt * 16 + lrow;
      const bf16x8 bfr = *(const bf16x8*)(smem + F_OFF_SB + c * 256 + (kb ^ ((c & 7) << 4)));
      acc_b[nt] = __builtin_amdgcn_mfma_f32_16x16x32_bf16(af[ks], bfr, acc_b[nt], 0, 0, 0);
    }
  }
  __syncthreads();
  stageB(256);
  __syncthreads();
  v4f accg = vzero;
#pragma unroll
  for (int ks = 0; ks < 4; ++ks) {
    const int kb = (ks * 32 + lko) * 2;
    const bf16x8 ag = *(const bf16x8*)(smem + F_OFF_GL + lrow * 256 + (kb ^ ((lrow & 7) << 4)));
    const int cg = wave * 16 + lrow;
    const bf16x8 bg = *(const bf16x8*)(smem + F_OFF_SB + cg * 256 + (kb ^ ((cg & 7) << 4)));
    accg = __builtin_amdgcn_mfma_f32_16x16x32_bf16(ag, bg, accg, 0, 0, 0);
  }
  __syncthreads();
  {
    const int rgb = (lane >> 4) * 4;
#pragma unroll
    for (int nt = 0; nt < 4; ++nt) {
      const int c = wnh * 64 + nt * 16 + lrow;
#pragma unroll
      for (int rg = 0; rg < 4; ++rg) {
        const int m = wmt * 16 + rgb + rg;
        const int sw = (c * 2) ^ ((m & 7) << 4);
        *(u16*)(smem + F_OFF_SB + m * 256 + sw)        = (u16)(asu(acc_a[nt][rg]) >> 16);
        *(u16*)(smem + F_OFF_SB + (64 + m) * 256 + sw) = (u16)(asu(acc_b[nt][rg]) >> 16);
      }
    }
    const int cg = wave * 16 + lrow;
    const float b1c = ((const float*)(smem + F_OFF_B1V))[cg];
#pragma unroll
    for (int rg = 0; rg < 4; ++rg) {
      const int bbr = rgb + rg;
      if (bbr < F_NB)
        *(u16*)(smem + F_OFF_A + bbr * 256 + ((cg * 2) ^ ((bbr & 7) << 4))) =
            (u16)(asu(accg[rg] + b1c) >> 16);
    }
  }
  __syncthreads();

  float b2n[4], w3n[4];
#pragma unroll
  for (int nt = 0; nt < 4; ++nt) {
    const int n = nt * 16 + lrow;
    b2n[nt] = ((const float*)(smem + F_OFF_B2V))[n];
    w3n[nt] = ((const float*)(smem + F_OFF_W3V))[n];
  }
  for (int t = wave; t < 14; t += 8) {
    const int r  = t * 16 + lrow;
    const int bb = (r * 9363) >> 18;
    const int p  = r - bb * 28;
    const unsigned pr8 = c_pair[p];
    const int mi = bb * 8 + (int)(pr8 >> 3);
    const int mj = 64 + bb * 8 + (int)(pr8 & 7);
    v4f acc2[4] = {vzero, vzero, vzero, vzero};
#pragma unroll
    for (int ks = 0; ks < 4; ++ks) {
      const int kb = (ks * 32 + lko) * 2;
      const u32x4 va = *(const u32x4*)(smem + F_OFF_SB + mi * 256 + (kb ^ ((mi & 7) << 4)));
      const u32x4 vb = *(const u32x4*)(smem + F_OFF_SB + mj * 256 + (kb ^ ((mj & 7) << 4)));
      const u32x4 vg = *(const u32x4*)(smem + F_OFF_A  + bb * 256 + (kb ^ ((bb & 7) << 4)));
      u32x4 a2;
#pragma unroll
      for (int w = 0; w < 4; ++w) {
        const float lo = fmaxf(lo2f(va[w]) + lo2f(vb[w]) + lo2f(vg[w]), 0.0f);
        const float hi = fmaxf(hi2f(va[w]) + hi2f(vb[w]) + hi2f(vg[w]), 0.0f);
        a2[w] = pkt(lo, hi);
      }
      union { u32x4 u; bf16x8 h; } cv; cv.u = a2;
#pragma unroll
      for (int nt = 0; nt < 4; ++nt) {
        const int c = nt * 16 + lrow;
        const bf16x8 w2fr = *(const bf16x8*)(smem + F_OFF_W2 + c * 256 + (kb ^ ((c & 7) << 4)));
        acc2[nt] = __builtin_amdgcn_mfma_f32_16x16x32_bf16(cv.h, w2fr, acc2[nt], 0, 0, 0);
      }
    }
    float part[4] = {0.f, 0.f, 0.f, 0.f};
#pragma unroll
    for (int nt = 0; nt < 4; ++nt)
#pragma unroll
      for (int rg = 0; rg < 4; ++rg)
        part[rg] += fmaxf(acc2[nt][rg] + b2n[nt], 0.0f) * w3n[nt];
#pragma unroll
    for (int mk = 1; mk < 16; mk <<= 1)
#pragma unroll
      for (int rg = 0; rg < 4; ++rg) part[rg] += __shfl_xor(part[rg], mk, 16);
    if ((lane & 15) == 0) {
      const int rb = t * 16 + (lane >> 4) * 4;
#pragma unroll
      for (int rg = 0; rg < 4; ++rg) {
        const int rr = rb + rg;
        const int b2_ = (rr * 9363) >> 18;
        const int p2  = rr - b2_ * 28;
        const size_t o = (size_t)(bb0 + b2_) * 28 + p2;
        outp[o] = dmask[o] ? (part[rg] + bias3) : -1.0e9f;
      }
    }
  }
}

extern "C" void kernel_launch(void* const* d_in, const int* in_sizes, int n_in,
                              void* d_out, int out_size, void* d_ws, size_t ws_size,
                              hipStream_t stream) {
  (void)in_sizes; (void)n_in; (void)out_size;
  const float* node = (const float*)d_in[0];
  const float* glob = (const float*)d_in[1];
  const int* dmsk   = (const int*)d_in[3];   // bool -> int32 on upload
  const float* W1 = (const float*)d_in[5];
  const float* b1 = (const float*)d_in[6];
  const float* W2 = (const float*)d_in[7];
  const float* b2 = (const float*)d_in[8];
  const float* W3 = (const float*)d_in[9];
  const float* b3 = (const float*)d_in[10];
  float* outp = (float*)d_out;

  if (ws_size >= (size_t)WS_NEED) {
    char* ws = (char*)d_ws;
    prep_weights<<<28, 1024, 0, stream>>>(W1, W2, ws);
    prep_gp<<<128, 256, 0, stream>>>(glob, b1, ws);
    docking_main<<<256, 1024, 0, stream>>>(node, dmsk, b2, W3, b3, ws, outp);
  } else {
    docking_fused<<<16384 / F_NB, F_THREADS, 0, stream>>>(node, glob, dmsk, W1, b1, W2, b2, W3, b3, outp);
  }
}

// Round 8
// 95.206 us; speedup vs baseline: 1.4388x; 1.4388x over previous
//
#include <hip/hip_runtime.h>

typedef float    v4f    __attribute__((ext_vector_type(4)));
typedef short    bf16x8 __attribute__((ext_vector_type(8)));
typedef unsigned u32x4  __attribute__((ext_vector_type(4)));
typedef unsigned short u16;

__constant__ unsigned char c_pair[28] = {
  1,2,3,4,5,6,7, 10,11,12,13,14,15, 19,20,21,22,23, 28,29,30,31, 37,38,39, 46,47, 55
};

static __device__ __forceinline__ unsigned asu(float f){ union{float f;unsigned u;}v; v.f=f; return v.u; }
static __device__ __forceinline__ float lo2f(unsigned d){ union{unsigned u;float f;}v; v.u = d<<16; return v.f; }
static __device__ __forceinline__ float hi2f(unsigned d){ union{unsigned u;float f;}v; v.u = d & 0xffff0000u; return v.f; }
static __device__ __forceinline__ unsigned pkt(float lo, float hi){
  return __builtin_amdgcn_perm(asu(hi), asu(lo), 0x07060302u);
}

// ---------------- ws image layout ----------------
#define WS_W1AB 0
#define WS_W1G  65536
#define WS_W2   98304
#define WS_GP   114688
#define WS_NEED 4308992

// ================= prep kernels =================
__global__ __launch_bounds__(1024)
void prep_weights(const float* __restrict__ W1, const float* __restrict__ W2, char* __restrict__ ws)
{
  const int idx = blockIdx.x * 1024 + threadIdx.x;   // 28 blocks * 1024 = 28672
  if (idx < 16384) {
    const int c = idx >> 6, kp = idx & 63;
    const int part = c >> 7, cc = c & 127;
    const float a  = W1[(size_t)(part * 128 + 2 * kp) * 128 + cc];
    const float b_ = W1[(size_t)(part * 128 + 2 * kp + 1) * 128 + cc];
    *(unsigned*)(ws + WS_W1AB + (size_t)c * 256 + ((kp * 4) ^ ((c & 7) << 4))) = pkt(a, b_);
  } else if (idx < 24576) {
    const int j = idx - 16384, c = j >> 6, kp = j & 63;
    const float a  = W1[(size_t)(256 + 2 * kp) * 128 + c];
    const float b_ = W1[(size_t)(256 + 2 * kp + 1) * 128 + c];
    *(unsigned*)(ws + WS_W1G + (size_t)c * 256 + ((kp * 4) ^ ((c & 7) << 4))) = pkt(a, b_);
  } else if (idx < 28672) {
    const int j = idx - 24576, c = j >> 6, kp = j & 63;
    const float a  = W2[(size_t)(2 * kp) * 64 + c];
    const float b_ = W2[(size_t)(2 * kp + 1) * 64 + c];
    *(unsigned*)(ws + WS_W2 + (size_t)c * 256 + ((kp * 4) ^ ((c & 7) << 4))) = pkt(a, b_);
  }
}

__global__ __launch_bounds__(256)
void prep_gp(const float* __restrict__ glob, const float* __restrict__ b1, char* __restrict__ ws)
{
  __shared__ __align__(16) char sm[65536];   // [0,32K) glob tile bf16 swz; [32K,64K) W1gT
  const int tid = threadIdx.x;
  const int bb0 = blockIdx.x * 128;          // 128 blocks x 128 batches
  for (int i = tid; i < 2048; i += 256) {
    const u32x4 v = *(const u32x4*)(ws + WS_W1G + i * 16);
    *(u32x4*)(sm + 32768 + i * 16) = v;
  }
  for (int i = tid; i < 4096; i += 256) {
    const int r = i >> 5, q = i & 31;
    const float4 f = *(const float4*)(glob + (size_t)(bb0 + r) * 128 + q * 4);
    int2 w; w.x = (int)pkt(f.x, f.y); w.y = (int)pkt(f.z, f.w);
    *(int2*)(sm + r * 256 + ((q * 8) ^ ((r & 7) << 4))) = w;
  }
  __syncthreads();
  const int wave = tid >> 6, lane = tid & 63, lrow = lane & 15, lko = (lane >> 4) * 8;
  float b1c[8];
#pragma unroll
  for (int nt = 0; nt < 8; ++nt) b1c[nt] = b1[nt * 16 + lrow];
  const v4f vzero = {0.f, 0.f, 0.f, 0.f};
  v4f acc[2][8];
#pragma unroll
  for (int mt = 0; mt < 2; ++mt)
#pragma unroll
    for (int nt = 0; nt < 8; ++nt) acc[mt][nt] = vzero;
#pragma unroll
  for (int ks = 0; ks < 4; ++ks) {
    const int kb = (ks * 32 + lko) * 2;
    bf16x8 af[2];
#pragma unroll
    for (int mt = 0; mt < 2; ++mt) {
      const int r = wave * 32 + mt * 16 + lrow;
      af[mt] = *(const bf16x8*)(sm + r * 256 + (kb ^ ((r & 7) << 4)));
    }
#pragma unroll
    for (int nt = 0; nt < 8; ++nt) {
      const int c = nt * 16 + lrow;
      const bf16x8 bfr = *(const bf16x8*)(sm + 32768 + c * 256 + (kb ^ ((c & 7) << 4)));
#pragma unroll
      for (int mt = 0; mt < 2; ++mt)
        acc[mt][nt] = __builtin_amdgcn_mfma_f32_16x16x32_bf16(af[mt], bfr, acc[mt][nt], 0, 0, 0);
    }
  }
#pragma unroll
  for (int mt = 0; mt < 2; ++mt)
#pragma unroll
    for (int nt = 0; nt < 8; ++nt) {
      const int c = nt * 16 + lrow;
#pragma unroll
      for (int rg = 0; rg < 4; ++rg) {
        const int m = wave * 32 + mt * 16 + (lane >> 4) * 4 + rg;
        const int batch = bb0 + m;
        const int g = batch >> 4, q = m & 15;
        *(u16*)(ws + WS_GP + (size_t)g * 4096 + q * 256 + ((c * 2) ^ ((q & 7) << 4))) =
            (u16)(asu(acc[mt][nt][rg] + b1c[nt]) >> 16);
      }
    }
}

// ================= main kernel =================
// 1024 blocks x 512 threads (8 waves); each block = ONE 16-batch tile.
// LDS = Pa(32K) + Pb(32K) + W2T(16K) = exactly 80 KiB -> 2 blocks/CU.
// Phase-1 A from node global (pack in reg); B-frags + gp read via L2 from ws.
// 512-thread geometry is the one proven NOT to spill at the 64-VGPR cap (R3).
#define M_OFF_PA  0        // 32768: Pa [128 rows][256B swz]
#define M_OFF_PB  32768    // 32768: Pb
#define M_OFF_W2  65536    // 16384: W2T rows 0..63
#define M_SMEM    81920

__global__ __launch_bounds__(512, 4)
void docking_main(const float* __restrict__ node, const int* __restrict__ dmask,
                  const float* __restrict__ b2, const float* __restrict__ W3,
                  const float* __restrict__ b3,
                  const char* __restrict__ ws, float* __restrict__ outp)
{
  __shared__ __align__(16) char smem[M_SMEM];
  const int tid = threadIdx.x;
  const int wave = tid >> 6, lane = tid & 63, lrow = lane & 15, lko = (lane >> 4) * 8;
  const int wm = wave >> 2, wn = wave & 3;       // 2 (M) x 4 (N)
  const int bb0 = blockIdx.x * 16;
  const float bias3 = *b3;
  const v4f vzero = {0.f, 0.f, 0.f, 0.f};

  // ---- stage W2T into LDS (pure 16B copies) ----
#pragma unroll
  for (int i = 0; i < 2; ++i) {
    const int j = tid + i * 512;
    const u32x4 v = *(const u32x4*)(ws + WS_W2 + j * 16);
    *(u32x4*)(smem + M_OFF_W2 + j * 16) = v;
  }
  // epilogue constants (8 persistent VGPRs)
  float b2n[4], w3n[4];
#pragma unroll
  for (int nt = 0; nt < 4; ++nt) {
    const int n = nt * 16 + lrow;
    b2n[nt] = b2[n]; w3n[nt] = W3[n];
  }

  // ---- phase 1: proj GEMM  M=128 N=256 K=128 ----
  // wave covers 4 m-tiles (wm half) x 4 n-tiles (wn quarter); per-mt acc[4].
  const char* wsW = ws + WS_W1AB;
  const int pbase = (wn >= 2) ? M_OFF_PB : M_OFF_PA;
  const int rgb = (lane >> 4) * 4;
  const float* aBase = node + ((size_t)bb0 * 8 + (size_t)wm * 64 + lrow) * 128 + lko;

#pragma unroll 1
  for (int mt = 0; mt < 4; ++mt) {
    const float* arow = aBase + mt * 2048;     // +16 rows
    v4f acc[4] = {vzero, vzero, vzero, vzero};

    auto loadA = [&](int ks) -> bf16x8 {
      const float* s = arow + ks * 32;
      const float4 f0 = *(const float4*)(s);
      const float4 f1 = *(const float4*)(s + 4);
      union { u32x4 u; bf16x8 h; } cv;
      cv.u[0] = pkt(f0.x, f0.y); cv.u[1] = pkt(f0.z, f0.w);
      cv.u[2] = pkt(f1.x, f1.y); cv.u[3] = pkt(f1.z, f1.w);
      return cv.h;
    };

    bf16x8 afc = loadA(0);
#pragma unroll 1
    for (int ks = 0; ks < 4; ++ks) {
      const bf16x8 afn = (ks < 3) ? loadA(ks + 1) : afc;
      const int kb = (ks * 32 + lko) * 2;
#pragma unroll
      for (int nt = 0; nt < 4; ++nt) {
        const int c = wn * 64 + nt * 16 + lrow;
        const bf16x8 bfr = *(const bf16x8*)(wsW + c * 256 + (kb ^ ((c & 7) << 4)));
        acc[nt] = __builtin_amdgcn_mfma_f32_16x16x32_bf16(afc, bfr, acc[nt], 0, 0, 0);
      }
      afc = afn;
    }
    // write this mt's proj (16 rows x 64 cols) into Pa/Pb
#pragma unroll
    for (int nt = 0; nt < 4; ++nt) {
      const int c = (wn & 1) * 64 + nt * 16 + lrow;
#pragma unroll
      for (int rg = 0; rg < 4; ++rg) {
        const int m = wm * 64 + mt * 16 + rgb + rg;
        *(u16*)(smem + pbase + m * 256 + ((c * 2) ^ ((m & 7) << 4))) =
            (u16)(asu(acc[nt][rg]) >> 16);
      }
    }
  }
  __syncthreads();   // W2T staged + Pa/Pb visible

  // ---- phase 2: pair MLP (28 tiles of 16 pair-rows over 8 waves) ----
  const char* gpBase = ws + WS_GP + (size_t)blockIdx.x * 4096;
#pragma unroll 1
  for (int t = wave; t < 28; t += 8) {
    const int r  = t * 16 + lrow;
    const int bb = (r * 9363) >> 18;               // r/28 for r<2340
    const int p  = r - bb * 28;
    const unsigned pr8 = c_pair[p];
    const int mi = bb * 8 + (int)(pr8 >> 3);
    const int mj = bb * 8 + (int)(pr8 & 7);

    v4f acc2[4] = {vzero, vzero, vzero, vzero};
#pragma unroll
    for (int ks = 0; ks < 4; ++ks) {
      const int kb = (ks * 32 + lko) * 2;
      const u32x4 va = *(const u32x4*)(smem + M_OFF_PA + mi * 256 + (kb ^ ((mi & 7) << 4)));
      const u32x4 vb = *(const u32x4*)(smem + M_OFF_PB + mj * 256 + (kb ^ ((mj & 7) << 4)));
      const u32x4 vg = *(const u32x4*)(gpBase + bb * 256 + (kb ^ ((bb & 7) << 4)));
      u32x4 a2;
#pragma unroll
      for (int w = 0; w < 4; ++w) {
        const float lo = fmaxf(lo2f(va[w]) + lo2f(vb[w]) + lo2f(vg[w]), 0.0f);
        const float hi = fmaxf(hi2f(va[w]) + hi2f(vb[w]) + hi2f(vg[w]), 0.0f);
        a2[w] = pkt(lo, hi);
      }
      union { u32x4 u; bf16x8 h; } cv; cv.u = a2;
#pragma unroll
      for (int nt = 0; nt < 4; ++nt) {
        const int cc = nt * 16 + lrow;
        const bf16x8 w2fr = *(const bf16x8*)(smem + M_OFF_W2 + cc * 256 + (kb ^ ((cc & 7) << 4)));
        acc2[nt] = __builtin_amdgcn_mfma_f32_16x16x32_bf16(cv.h, w2fr, acc2[nt], 0, 0, 0);
      }
    }
    float part[4] = {0.f, 0.f, 0.f, 0.f};
#pragma unroll
    for (int nt = 0; nt < 4; ++nt)
#pragma unroll
      for (int rg = 0; rg < 4; ++rg)
        part[rg] += fmaxf(acc2[nt][rg] + b2n[nt], 0.0f) * w3n[nt];
#pragma unroll
    for (int mk = 1; mk < 16; mk <<= 1)
#pragma unroll
      for (int rg = 0; rg < 4; ++rg) part[rg] += __shfl_xor(part[rg], mk, 16);

    if ((lane & 15) == 0) {
      const int rb = t * 16 + (lane >> 4) * 4;
#pragma unroll
      for (int rg = 0; rg < 4; ++rg) {
        const int rr = rb + rg;
        const int b2_ = (rr * 9363) >> 18;
        const int p2  = rr - b2_ * 28;
        const size_t o = (size_t)(bb0 + b2_) * 28 + p2;
        outp[o] = dmask[o] ? (part[rg] + bias3) : -1.0e9f;
      }
    }
  }
}

// ================= fallback (proven R3 fused kernel) =================
#define F_THREADS 512
#define F_NB      8
#define F_OFF_A    0
#define F_OFF_GL   16384
#define F_OFF_SB   20480
#define F_OFF_W2   53248
#define F_OFF_B1V  69632
#define F_OFF_B2V  70144
#define F_OFF_W3V  70400
#define F_SMEM     70656

__global__ __launch_bounds__(F_THREADS, 4)
void docking_fused(const float* __restrict__ node, const float* __restrict__ glob,
                   const int* __restrict__ dmask,
                   const float* __restrict__ W1, const float* __restrict__ b1,
                   const float* __restrict__ W2, const float* __restrict__ b2,
                   const float* __restrict__ W3, const float* __restrict__ b3,
                   float* __restrict__ outp)
{
  __shared__ __align__(16) char smem[F_SMEM];
  const int tid = threadIdx.x;
  const int bb0 = blockIdx.x * F_NB;
  const size_t nrow0 = (size_t)bb0 * 8;
  const float bias3 = *b3;

  if (tid < 128)      ((float*)(smem + F_OFF_B1V))[tid]       = b1[tid];
  else if (tid < 192) ((float*)(smem + F_OFF_B2V))[tid - 128] = b2[tid - 128];
  else if (tid < 256) ((float*)(smem + F_OFF_W3V))[tid - 192] = W3[tid - 192];

  for (int idx = tid; idx < 64 * 32; idx += F_THREADS) {
    const int r = idx >> 5, q = idx & 31;
    const float4 f = *(const float4*)(node + (nrow0 + (size_t)r) * 128 + q * 4);
    int2 w; w.x = (int)pkt(f.x, f.y); w.y = (int)pkt(f.z, f.w);
    *(int2*)(smem + F_OFF_A + r * 256 + ((q * 8) ^ ((r & 7) << 4))) = w;
  }
  for (int idx = tid; idx < 16 * 32; idx += F_THREADS) {
    const int r = idx >> 5, q = idx & 31;
    float4 f = make_float4(0.f, 0.f, 0.f, 0.f);
    if (r < F_NB) f = *(const float4*)(glob + (size_t)(bb0 + r) * 128 + q * 4);
    int2 w; w.x = (int)pkt(f.x, f.y); w.y = (int)pkt(f.z, f.w);
    *(int2*)(smem + F_OFF_GL + r * 256 + ((q * 8) ^ ((r & 7) << 4))) = w;
  }
  for (int idx = tid; idx < 4096; idx += F_THREADS) {
    const int cl = idx & 7, kl = (idx >> 3) & 7, ch = (idx >> 6) & 7, kh = idx >> 9;
    const int c = cl | (ch << 3), kp = kl | (kh << 3);
    const float a  = W2[(size_t)(2 * kp) * 64 + c];
    const float b_ = W2[(size_t)(2 * kp + 1) * 64 + c];
    *(unsigned*)(smem + F_OFF_W2 + c * 256 + ((kp * 4) ^ ((c & 7) << 4))) = pkt(a, b_);
  }
  auto stageB = [&](int rowOff) {
    for (int idx = tid; idx < 8192; idx += F_THREADS) {
      const int cl = idx & 7, kl = (idx >> 3) & 7, ch = (idx >> 6) & 15, kh = idx >> 10;
      const int c = cl | (ch << 3), kp = kl | (kh << 3);
      const float a  = W1[(size_t)(rowOff + 2 * kp) * 128 + c];
      const float b_ = W1[(size_t)(rowOff + 2 * kp + 1) * 128 + c];
      *(unsigned*)(smem + F_OFF_SB + c * 256 + ((kp * 4) ^ ((c & 7) << 4))) = pkt(a, b_);
    }
  };
  stageB(0);
  __syncthreads();

  const int wave = tid >> 6, lane = tid & 63;
  const int lrow = lane & 15;
  const int lko  = (lane >> 4) * 8;
  const int wmt = wave >> 1, wnh = wave & 1;
  const v4f vzero = {0.f, 0.f, 0.f, 0.f};

  bf16x8 af[4];
#pragma unroll
  for (int ks = 0; ks < 4; ++ks) {
    const int r = wmt * 16 + lrow;
    af[ks] = *(const bf16x8*)(smem + F_OFF_A + r * 256 + (((ks * 32 + lko) * 2) ^ ((r & 7) << 4)));
  }
  v4f acc_a[4] = {vzero, vzero, vzero, vzero};
#pragma unroll
  for (int ks = 0; ks < 4; ++ks) {
    const int kb = (ks * 32 + lko) * 2;
#pragma unroll
    for (int nt = 0; nt < 4; ++nt) {
      const int c = wnh * 64 + nt * 16 + lrow;
      const bf16x8 bfr = *(const bf16x8*)(smem + F_OFF_SB + c * 256 + (kb ^ ((c & 7) << 4)));
      acc_a[nt] = __builtin_amdgcn_mfma_f32_16x16x32_bf16(af[ks], bfr, acc_a[nt], 0, 0, 0);
    }
  }
  __syncthreads();
  stageB(128);
  __syncthreads();
  v4f acc_b[4] = {vzero, vzero, vzero, vzero};
#pragma unroll
  for (int ks = 0; ks < 4; ++ks) {
    const int kb = (ks * 32 + lko) * 2;
#pragma unroll
    for (int nt = 0; nt < 4; ++nt) {
      const int c = wnh * 64 + nt * 16 + lrow;
      const bf16x8 bfr = *(const bf16x8*)(smem + F_OFF_SB + c * 256 + (kb ^ ((c & 7) << 4)));
      acc_b[nt] = __builtin_amdgcn_mfma_f32_16x16x32_bf16(af[ks], bfr, acc_b[nt], 0, 0, 0);
    }
  }
  __syncthreads();
  stageB(256);
  __syncthreads();
  v4f accg = vzero;
#pragma unroll
  for (int ks = 0; ks < 4; ++ks) {
    const int kb = (ks * 32 + lko) * 2;
    const bf16x8 ag = *(const bf16x8*)(smem + F_OFF_GL + lrow * 256 + (kb ^ ((lrow & 7) << 4)));
    const int cg = wave * 16 + lrow;
    const bf16x8 bg = *(const bf16x8*)(smem + F_OFF_SB + cg * 256 + (kb ^ ((cg & 7) << 4)));
    accg = __builtin_amdgcn_mfma_f32_16x16x32_bf16(ag, bg, accg, 0, 0, 0);
  }
  __syncthreads();
  {
    const int rgb = (lane >> 4) * 4;
#pragma unroll
    for (int nt = 0; nt < 4; ++nt) {
      const int c = wnh * 64 + nt * 16 + lrow;
#pragma unroll
      for (int rg = 0; rg < 4; ++rg) {
        const int m = wmt * 16 + rgb + rg;
        const int sw = (c * 2) ^ ((m & 7) << 4);
        *(u16*)(smem + F_OFF_SB + m * 256 + sw)        = (u16)(asu(acc_a[nt][rg]) >> 16);
        *(u16*)(smem + F_OFF_SB + (64 + m) * 256 + sw) = (u16)(asu(acc_b[nt][rg]) >> 16);
      }
    }
    const int cg = wave * 16 + lrow;
    const float b1c = ((const float*)(smem + F_OFF_B1V))[cg];
#pragma unroll
    for (int rg = 0; rg < 4; ++rg) {
      const int bbr = rgb + rg;
      if (bbr < F_NB)
        *(u16*)(smem + F_OFF_A + bbr * 256 + ((cg * 2) ^ ((bbr & 7) << 4))) =
            (u16)(asu(accg[rg] + b1c) >> 16);
    }
  }
  __syncthreads();

  float b2n[4], w3n[4];
#pragma unroll
  for (int nt = 0; nt < 4; ++nt) {
    const int n = nt * 16 + lrow;
    b2n[nt] = ((const float*)(smem + F_OFF_B2V))[n];
    w3n[nt] = ((const float*)(smem + F_OFF_W3V))[n];
  }
  for (int t = wave; t < 14; t += 8) {
    const int r  = t * 16 + lrow;
    const int bb = (r * 9363) >> 18;
    const int p  = r - bb * 28;
    const unsigned pr8 = c_pair[p];
    const int mi = bb * 8 + (int)(pr8 >> 3);
    const int mj = 64 + bb * 8 + (int)(pr8 & 7);
    v4f acc2[4] = {vzero, vzero, vzero, vzero};
#pragma unroll
    for (int ks = 0; ks < 4; ++ks) {
      const int kb = (ks * 32 + lko) * 2;
      const u32x4 va = *(const u32x4*)(smem + F_OFF_SB + mi * 256 + (kb ^ ((mi & 7) << 4)));
      const u32x4 vb = *(const u32x4*)(smem + F_OFF_SB + mj * 256 + (kb ^ ((mj & 7) << 4)));
      const u32x4 vg = *(const u32x4*)(smem + F_OFF_A  + bb * 256 + (kb ^ ((bb & 7) << 4)));
      u32x4 a2;
#pragma unroll
      for (int w = 0; w < 4; ++w) {
        const float lo = fmaxf(lo2f(va[w]) + lo2f(vb[w]) + lo2f(vg[w]), 0.0f);
        const float hi = fmaxf(hi2f(va[w]) + hi2f(vb[w]) + hi2f(vg[w]), 0.0f);
        a2[w] = pkt(lo, hi);
      }
      union { u32x4 u; bf16x8 h; } cv; cv.u = a2;
#pragma unroll
      for (int nt = 0; nt < 4; ++nt) {
        const int c = nt * 16 + lrow;
        const bf16x8 w2fr = *(const bf16x8*)(smem + F_OFF_W2 + c * 256 + (kb ^ ((c & 7) << 4)));
        acc2[nt] = __builtin_amdgcn_mfma_f32_16x16x32_bf16(cv.h, w2fr, acc2[nt], 0, 0, 0);
      }
    }
    float part[4] = {0.f, 0.f, 0.f, 0.f};
#pragma unroll
    for (int nt = 0; nt < 4; ++nt)
#pragma unroll
      for (int rg = 0; rg < 4; ++rg)
        part[rg] += fmaxf(acc2[nt][rg] + b2n[nt], 0.0f) * w3n[nt];
#pragma unroll
    for (int mk = 1; mk < 16; mk <<= 1)
#pragma unroll
      for (int rg = 0; rg < 4; ++rg) part[rg] += __shfl_xor(part[rg], mk, 16);
    if ((lane & 15) == 0) {
      const int rb = t * 16 + (lane >> 4) * 4;
#pragma unroll
      for (int rg = 0; rg < 4; ++rg) {
        const int rr = rb + rg;
        const int b2_ = (rr * 9363) >> 18;
        const int p2  = rr - b2_ * 28;
        const size_t o = (size_t)(bb0 + b2_) * 28 + p2;
        outp[o] = dmask[o] ? (part[rg] + bias3) : -1.0e9f;
      }
    }
  }
}

extern "C" void kernel_launch(void* const* d_in, const int* in_sizes, int n_in,
                              void* d_out, int out_size, void* d_ws, size_t ws_size,
                              hipStream_t stream) {
  (void)in_sizes; (void)n_in; (void)out_size;
  const float* node = (const float*)d_in[0];
  const float* glob = (const float*)d_in[1];
  const int* dmsk   = (const int*)d_in[3];   // bool -> int32 on upload
  const float* W1 = (const float*)d_in[5];
  const float* b1 = (const float*)d_in[6];
  const float* W2 = (const float*)d_in[7];
  const float* b2 = (const float*)d_in[8];
  const float* W3 = (const float*)d_in[9];
  const float* b3 = (const float*)d_in[10];
  float* outp = (float*)d_out;

  if (ws_size >= (size_t)WS_NEED) {
    char* ws = (char*)d_ws;
    prep_weights<<<28, 1024, 0, stream>>>(W1, W2, ws);
    prep_gp<<<128, 256, 0, stream>>>(glob, b1, ws);
    docking_main<<<1024, 512, 0, stream>>>(node, dmsk, b2, W3, b3, ws, outp);
  } else {
    docking_fused<<<16384 / F_NB, F_THREADS, 0, stream>>>(node, glob, dmsk, W1, b1, W2, b2, W3, b3, outp);
  }
}

// Round 9
// 81.402 us; speedup vs baseline: 1.6827x; 1.1696x over previous
//
#include <hip/hip_runtime.h>

typedef float    v4f    __attribute__((ext_vector_type(4)));
typedef short    bf16x8 __attribute__((ext_vector_type(8)));
typedef unsigned u32x4  __attribute__((ext_vector_type(4)));
typedef unsigned short u16;

__constant__ unsigned char c_pair[28] = {
  1,2,3,4,5,6,7, 10,11,12,13,14,15, 19,20,21,22,23, 28,29,30,31, 37,38,39, 46,47, 55
};

static __device__ __forceinline__ unsigned asu(float f){ union{float f;unsigned u;}v; v.f=f; return v.u; }
static __device__ __forceinline__ float lo2f(unsigned d){ union{unsigned u;float f;}v; v.u = d<<16; return v.f; }
static __device__ __forceinline__ float hi2f(unsigned d){ union{unsigned u;float f;}v; v.u = d & 0xffff0000u; return v.f; }
static __device__ __forceinline__ unsigned pkt(float lo, float hi){
  return __builtin_amdgcn_perm(asu(hi), asu(lo), 0x07060302u);
}

// ---------------- ws image layout ----------------
#define WS_W1AB 0
#define WS_W1G  65536
#define WS_W2   98304
#define WS_GP   114688
#define WS_NEED 4308992

// ================= prep kernels =================
__global__ __launch_bounds__(1024)
void prep_weights(const float* __restrict__ W1, const float* __restrict__ W2, char* __restrict__ ws)
{
  const int idx = blockIdx.x * 1024 + threadIdx.x;   // 28 blocks * 1024 = 28672
  if (idx < 16384) {
    const int c = idx >> 6, kp = idx & 63;
    const int part = c >> 7, cc = c & 127;
    const float a  = W1[(size_t)(part * 128 + 2 * kp) * 128 + cc];
    const float b_ = W1[(size_t)(part * 128 + 2 * kp + 1) * 128 + cc];
    *(unsigned*)(ws + WS_W1AB + (size_t)c * 256 + ((kp * 4) ^ ((c & 7) << 4))) = pkt(a, b_);
  } else if (idx < 24576) {
    const int j = idx - 16384, c = j >> 6, kp = j & 63;
    const float a  = W1[(size_t)(256 + 2 * kp) * 128 + c];
    const float b_ = W1[(size_t)(256 + 2 * kp + 1) * 128 + c];
    *(unsigned*)(ws + WS_W1G + (size_t)c * 256 + ((kp * 4) ^ ((c & 7) << 4))) = pkt(a, b_);
  } else if (idx < 28672) {
    const int j = idx - 24576, c = j >> 6, kp = j & 63;
    const float a  = W2[(size_t)(2 * kp) * 64 + c];
    const float b_ = W2[(size_t)(2 * kp + 1) * 64 + c];
    *(unsigned*)(ws + WS_W2 + (size_t)c * 256 + ((kp * 4) ^ ((c & 7) << 4))) = pkt(a, b_);
  }
}

__global__ __launch_bounds__(256)
void prep_gp(const float* __restrict__ glob, const float* __restrict__ b1, char* __restrict__ ws)
{
  __shared__ __align__(16) char sm[65536];   // [0,32K) glob tile bf16 swz; [32K,64K) W1gT
  const int tid = threadIdx.x;
  const int bb0 = blockIdx.x * 128;          // 128 blocks x 128 batches
  for (int i = tid; i < 2048; i += 256) {
    const u32x4 v = *(const u32x4*)(ws + WS_W1G + i * 16);
    *(u32x4*)(sm + 32768 + i * 16) = v;
  }
  for (int i = tid; i < 4096; i += 256) {
    const int r = i >> 5, q = i & 31;
    const float4 f = *(const float4*)(glob + (size_t)(bb0 + r) * 128 + q * 4);
    int2 w; w.x = (int)pkt(f.x, f.y); w.y = (int)pkt(f.z, f.w);
    *(int2*)(sm + r * 256 + ((q * 8) ^ ((r & 7) << 4))) = w;
  }
  __syncthreads();
  const int wave = tid >> 6, lane = tid & 63, lrow = lane & 15, lko = (lane >> 4) * 8;
  float b1c[8];
#pragma unroll
  for (int nt = 0; nt < 8; ++nt) b1c[nt] = b1[nt * 16 + lrow];
  const v4f vzero = {0.f, 0.f, 0.f, 0.f};
  v4f acc[2][8];
#pragma unroll
  for (int mt = 0; mt < 2; ++mt)
#pragma unroll
    for (int nt = 0; nt < 8; ++nt) acc[mt][nt] = vzero;
#pragma unroll
  for (int ks = 0; ks < 4; ++ks) {
    const int kb = (ks * 32 + lko) * 2;
    bf16x8 af[2];
#pragma unroll
    for (int mt = 0; mt < 2; ++mt) {
      const int r = wave * 32 + mt * 16 + lrow;
      af[mt] = *(const bf16x8*)(sm + r * 256 + (kb ^ ((r & 7) << 4)));
    }
#pragma unroll
    for (int nt = 0; nt < 8; ++nt) {
      const int c = nt * 16 + lrow;
      const bf16x8 bfr = *(const bf16x8*)(sm + 32768 + c * 256 + (kb ^ ((c & 7) << 4)));
#pragma unroll
      for (int mt = 0; mt < 2; ++mt)
        acc[mt][nt] = __builtin_amdgcn_mfma_f32_16x16x32_bf16(af[mt], bfr, acc[mt][nt], 0, 0, 0);
    }
  }
#pragma unroll
  for (int mt = 0; mt < 2; ++mt)
#pragma unroll
    for (int nt = 0; nt < 8; ++nt) {
      const int c = nt * 16 + lrow;
#pragma unroll
      for (int rg = 0; rg < 4; ++rg) {
        const int m = wave * 32 + mt * 16 + (lane >> 4) * 4 + rg;
        const int batch = bb0 + m;
        const int g = batch >> 4, q = m & 15;
        *(u16*)(ws + WS_GP + (size_t)g * 4096 + q * 256 + ((c * 2) ^ ((q & 7) << 4))) =
            (u16)(asu(acc[mt][nt][rg] + b1c[nt]) >> 16);
      }
    }
}

// ================= main kernel =================
// 2048 blocks x 512 threads (8 waves); each block = ONE 8-batch tile (64 node rows).
// LDS = Pa(16K) + Pb'(16K) + W2T(16K) + gp f32(4K) = 52 KiB -> 3 blocks/CU (24 waves).
// gp is folded into Pb at phase-1 write time: phase 2 reads only Pa + Pb'.
#define M2_PA   0        // 16384: Pa  [64 rows][256B swz]
#define M2_PB   16384    // 16384: Pb' [64 rows][256B swz]  (pb + gp + b1)
#define M2_W2   32768    // 16384: W2T rows 0..63
#define M2_GP   49152    // 4096 : gp f32 [8][128]
#define M2_SMEM 53248

__global__ __launch_bounds__(512)
void docking_main(const float* __restrict__ node, const int* __restrict__ dmask,
                  const float* __restrict__ b2, const float* __restrict__ W3,
                  const float* __restrict__ b3,
                  const char* __restrict__ ws, float* __restrict__ outp)
{
  __shared__ __align__(16) char smem[M2_SMEM];
  const int tid = threadIdx.x;
  const int wave = tid >> 6, lane = tid & 63, lrow = lane & 15, lko = (lane >> 4) * 8;
  const int wm = wave >> 2, wn = wave & 3;       // 2 (M-halves of 32 rows) x 4 (N)
  const int bb0 = blockIdx.x * 8;
  const float bias3 = *b3;
  const v4f vzero = {0.f, 0.f, 0.f, 0.f};

  // ---- stage W2T (16B copies) + gp tile (bf16 -> f32 unpack) ----
#pragma unroll
  for (int i = 0; i < 2; ++i) {
    const int j = tid + i * 512;
    const u32x4 v = *(const u32x4*)(ws + WS_W2 + j * 16);
    *(u32x4*)(smem + M2_W2 + j * 16) = v;
  }
  {
    const int q = tid >> 6, cp = tid & 63;                     // 8 rows x 64 u32
    const int qq = (bb0 & 15) + q;
    const unsigned v = *(const unsigned*)(ws + WS_GP + ((size_t)(bb0 >> 4)) * 4096
                                          + qq * 256 + ((cp * 4) ^ ((qq & 7) << 4)));
    float* gq = (float*)(smem + M2_GP) + q * 128;
    gq[cp * 2] = lo2f(v); gq[cp * 2 + 1] = hi2f(v);
  }
  // epilogue constants
  float b2n[4], w3n[4];
#pragma unroll
  for (int nt = 0; nt < 4; ++nt) {
    const int n = nt * 16 + lrow;
    b2n[nt] = b2[n]; w3n[nt] = W3[n];
  }
  __syncthreads();                                   // (A) W2T + gp visible

  // ---- phase 1: proj GEMM  M=64 N=256 K=128; A from global, B via L2 ----
  const char* wsW = ws + WS_W1AB;
  const int pbase = (wn >= 2) ? M2_PB : M2_PA;
  const int rgb = (lane >> 4) * 4;
  const float* aBase = node + ((size_t)bb0 * 8 + (size_t)wm * 32 + lrow) * 128 + lko;
  const float* sgp = (const float*)(smem + M2_GP);

  for (int mt = 0; mt < 2; ++mt) {
    const float* arow = aBase + mt * 16 * 128;
    v4f acc[4] = {vzero, vzero, vzero, vzero};
#pragma unroll
    for (int ks = 0; ks < 4; ++ks) {
      const float* s = arow + ks * 32;
      const float4 f0 = *(const float4*)(s);
      const float4 f1 = *(const float4*)(s + 4);
      union { u32x4 u; bf16x8 h; } cv;
      cv.u[0] = pkt(f0.x, f0.y); cv.u[1] = pkt(f0.z, f0.w);
      cv.u[2] = pkt(f1.x, f1.y); cv.u[3] = pkt(f1.z, f1.w);
      const int kb = (ks * 32 + lko) * 2;
#pragma unroll
      for (int nt = 0; nt < 4; ++nt) {
        const int c = wn * 64 + nt * 16 + lrow;
        const bf16x8 bfr = *(const bf16x8*)(wsW + c * 256 + (kb ^ ((c & 7) << 4)));
        acc[nt] = __builtin_amdgcn_mfma_f32_16x16x32_bf16(cv.h, bfr, acc[nt], 0, 0, 0);
      }
    }
    // write proj; Pb waves fold gp (+b1) in
#pragma unroll
    for (int nt = 0; nt < 4; ++nt) {
      const int c = (wn & 1) * 64 + nt * 16 + lrow;
#pragma unroll
      for (int rg = 0; rg < 4; ++rg) {
        const int m = wm * 32 + mt * 16 + rgb + rg;
        float v = acc[nt][rg];
        if (wn >= 2) v += sgp[(m >> 3) * 128 + c];
        *(u16*)(smem + pbase + m * 256 + ((c * 2) ^ ((m & 7) << 4))) =
            (u16)(asu(v) >> 16);
      }
    }
  }
  __syncthreads();                                   // (B) Pa/Pb' visible

  // ---- phase 2: pair MLP (14 tiles of 16 pair-rows over 8 waves) ----
  for (int t = wave; t < 14; t += 8) {
    const int r  = t * 16 + lrow;                    // 0..223
    const int bb = (r * 9363) >> 18;                 // r/28 for r<2340
    const int p  = r - bb * 28;
    const unsigned pr8 = c_pair[p];
    const int mi = bb * 8 + (int)(pr8 >> 3);
    const int mj = bb * 8 + (int)(pr8 & 7);

    v4f acc2[4] = {vzero, vzero, vzero, vzero};
#pragma unroll
    for (int ks = 0; ks < 4; ++ks) {
      const int kb = (ks * 32 + lko) * 2;
      const u32x4 va = *(const u32x4*)(smem + M2_PA + mi * 256 + (kb ^ ((mi & 7) << 4)));
      const u32x4 vb = *(const u32x4*)(smem + M2_PB + mj * 256 + (kb ^ ((mj & 7) << 4)));
      u32x4 a2;
#pragma unroll
      for (int w = 0; w < 4; ++w) {
        const float lo = fmaxf(lo2f(va[w]) + lo2f(vb[w]), 0.0f);
        const float hi = fmaxf(hi2f(va[w]) + hi2f(vb[w]), 0.0f);
        a2[w] = pkt(lo, hi);
      }
      union { u32x4 u; bf16x8 h; } cv; cv.u = a2;
#pragma unroll
      for (int nt = 0; nt < 4; ++nt) {
        const int cc = nt * 16 + lrow;
        const bf16x8 w2fr = *(const bf16x8*)(smem + M2_W2 + cc * 256 + (kb ^ ((cc & 7) << 4)));
        acc2[nt] = __builtin_amdgcn_mfma_f32_16x16x32_bf16(cv.h, w2fr, acc2[nt], 0, 0, 0);
      }
    }
    float part[4] = {0.f, 0.f, 0.f, 0.f};
#pragma unroll
    for (int nt = 0; nt < 4; ++nt)
#pragma unroll
      for (int rg = 0; rg < 4; ++rg)
        part[rg] += fmaxf(acc2[nt][rg] + b2n[nt], 0.0f) * w3n[nt];
#pragma unroll
    for (int mk = 1; mk < 16; mk <<= 1)
#pragma unroll
      for (int rg = 0; rg < 4; ++rg) part[rg] += __shfl_xor(part[rg], mk, 16);

    if ((lane & 15) == 0) {
      const int rb = t * 16 + (lane >> 4) * 4;
#pragma unroll
      for (int rg = 0; rg < 4; ++rg) {
        const int rr = rb + rg;
        const int b2_ = (rr * 9363) >> 18;
        const int p2  = rr - b2_ * 28;
        const size_t o = (size_t)(bb0 + b2_) * 28 + p2;
        outp[o] = dmask[o] ? (part[rg] + bias3) : -1.0e9f;
      }
    }
  }
}

// ================= fallback (proven R3 fused kernel) =================
#define F_THREADS 512
#define F_NB      8
#define F_OFF_A    0
#define F_OFF_GL   16384
#define F_OFF_SB   20480
#define F_OFF_W2   53248
#define F_OFF_B1V  69632
#define F_OFF_B2V  70144
#define F_OFF_W3V  70400
#define F_SMEM     70656

__global__ __launch_bounds__(F_THREADS, 4)
void docking_fused(const float* __restrict__ node, const float* __restrict__ glob,
                   const int* __restrict__ dmask,
                   const float* __restrict__ W1, const float* __restrict__ b1,
                   const float* __restrict__ W2, const float* __restrict__ b2,
                   const float* __restrict__ W3, const float* __restrict__ b3,
                   float* __restrict__ outp)
{
  __shared__ __align__(16) char smem[F_SMEM];
  const int tid = threadIdx.x;
  const int bb0 = blockIdx.x * F_NB;
  const size_t nrow0 = (size_t)bb0 * 8;
  const float bias3 = *b3;

  if (tid < 128)      ((float*)(smem + F_OFF_B1V))[tid]       = b1[tid];
  else if (tid < 192) ((float*)(smem + F_OFF_B2V))[tid - 128] = b2[tid - 128];
  else if (tid < 256) ((float*)(smem + F_OFF_W3V))[tid - 192] = W3[tid - 192];

  for (int idx = tid; idx < 64 * 32; idx += F_THREADS) {
    const int r = idx >> 5, q = idx & 31;
    const float4 f = *(const float4*)(node + (nrow0 + (size_t)r) * 128 + q * 4);
    int2 w; w.x = (int)pkt(f.x, f.y); w.y = (int)pkt(f.z, f.w);
    *(int2*)(smem + F_OFF_A + r * 256 + ((q * 8) ^ ((r & 7) << 4))) = w;
  }
  for (int idx = tid; idx < 16 * 32; idx += F_THREADS) {
    const int r = idx >> 5, q = idx & 31;
    float4 f = make_float4(0.f, 0.f, 0.f, 0.f);
    if (r < F_NB) f = *(const float4*)(glob + (size_t)(bb0 + r) * 128 + q * 4);
    int2 w; w.x = (int)pkt(f.x, f.y); w.y = (int)pkt(f.z, f.w);
    *(int2*)(smem + F_OFF_GL + r * 256 + ((q * 8) ^ ((r & 7) << 4))) = w;
  }
  for (int idx = tid; idx < 4096; idx += F_THREADS) {
    const int cl = idx & 7, kl = (idx >> 3) & 7, ch = (idx >> 6) & 7, kh = idx >> 9;
    const int c = cl | (ch << 3), kp = kl | (kh << 3);
    const float a  = W2[(size_t)(2 * kp) * 64 + c];
    const float b_ = W2[(size_t)(2 * kp + 1) * 64 + c];
    *(unsigned*)(smem + F_OFF_W2 + c * 256 + ((kp * 4) ^ ((c & 7) << 4))) = pkt(a, b_);
  }
  auto stageB = [&](int rowOff) {
    for (int idx = tid; idx < 8192; idx += F_THREADS) {
      const int cl = idx & 7, kl = (idx >> 3) & 7, ch = (idx >> 6) & 15, kh = idx >> 10;
      const int c = cl | (ch << 3), kp = kl | (kh << 3);
      const float a  = W1[(size_t)(rowOff + 2 * kp) * 128 + c];
      const float b_ = W1[(size_t)(rowOff + 2 * kp + 1) * 128 + c];
      *(unsigned*)(smem + F_OFF_SB + c * 256 + ((kp * 4) ^ ((c & 7) << 4))) = pkt(a, b_);
    }
  };
  stageB(0);
  __syncthreads();

  const int wave = tid >> 6, lane = tid & 63;
  const int lrow = lane & 15;
  const int lko  = (lane >> 4) * 8;
  const int wmt = wave >> 1, wnh = wave & 1;
  const v4f vzero = {0.f, 0.f, 0.f, 0.f};

  bf16x8 af[4];
#pragma unroll
  for (int ks = 0; ks < 4; ++ks) {
    const int r = wmt * 16 + lrow;
    af[ks] = *(const bf16x8*)(smem + F_OFF_A + r * 256 + (((ks * 32 + lko) * 2) ^ ((r & 7) << 4)));
  }
  v4f acc_a[4] = {vzero, vzero, vzero, vzero};
#pragma unroll
  for (int ks = 0; ks < 4; ++ks) {
    const int kb = (ks * 32 + lko) * 2;
#pragma unroll
    for (int nt = 0; nt < 4; ++nt) {
      const int c = wnh * 64 + nt * 16 + lrow;
      const bf16x8 bfr = *(const bf16x8*)(smem + F_OFF_SB + c * 256 + (kb ^ ((c & 7) << 4)));
      acc_a[nt] = __builtin_amdgcn_mfma_f32_16x16x32_bf16(af[ks], bfr, acc_a[nt], 0, 0, 0);
    }
  }
  __syncthreads();
  stageB(128);
  __syncthreads();
  v4f acc_b[4] = {vzero, vzero, vzero, vzero};
#pragma unroll
  for (int ks = 0; ks < 4; ++ks) {
    const int kb = (ks * 32 + lko) * 2;
#pragma unroll
    for (int nt = 0; nt < 4; ++nt) {
      const int c = wnh * 64 + nt * 16 + lrow;
      const bf16x8 bfr = *(const bf16x8*)(smem + F_OFF_SB + c * 256 + (kb ^ ((c & 7) << 4)));
      acc_b[nt] = __builtin_amdgcn_mfma_f32_16x16x32_bf16(af[ks], bfr, acc_b[nt], 0, 0, 0);
    }
  }
  __syncthreads();
  stageB(256);
  __syncthreads();
  v4f accg = vzero;
#pragma unroll
  for (int ks = 0; ks < 4; ++ks) {
    const int kb = (ks * 32 + lko) * 2;
    const bf16x8 ag = *(const bf16x8*)(smem + F_OFF_GL + lrow * 256 + (kb ^ ((lrow & 7) << 4)));
    const int cg = wave * 16 + lrow;
    const bf16x8 bg = *(const bf16x8*)(smem + F_OFF_SB + cg * 256 + (kb ^ ((cg & 7) << 4)));
    accg = __builtin_amdgcn_mfma_f32_16x16x32_bf16(ag, bg, accg, 0, 0, 0);
  }
  __syncthreads();
  {
    const int rgb = (lane >> 4) * 4;
#pragma unroll
    for (int nt = 0; nt < 4; ++nt) {
      const int c = wnh * 64 + nt * 16 + lrow;
#pragma unroll
      for (int rg = 0; rg < 4; ++rg) {
        const int m = wmt * 16 + rgb + rg;
        const int sw = (c * 2) ^ ((m & 7) << 4);
        *(u16*)(smem + F_OFF_SB + m * 256 + sw)        = (u16)(asu(acc_a[nt][rg]) >> 16);
        *(u16*)(smem + F_OFF_SB + (64 + m) * 256 + sw) = (u16)(asu(acc_b[nt][rg]) >> 16);
      }
    }
    const int cg = wave * 16 + lrow;
    const float b1c = ((const float*)(smem + F_OFF_B1V))[cg];
#pragma unroll
    for (int rg = 0; rg < 4; ++rg) {
      const int bbr = rgb + rg;
      if (bbr < F_NB)
        *(u16*)(smem + F_OFF_A + bbr * 256 + ((cg * 2) ^ ((bbr & 7) << 4))) =
            (u16)(asu(accg[rg] + b1c) >> 16);
    }
  }
  __syncthreads();

  float b2n[4], w3n[4];
#pragma unroll
  for (int nt = 0; nt < 4; ++nt) {
    const int n = nt * 16 + lrow;
    b2n[nt] = ((const float*)(smem + F_OFF_B2V))[n];
    w3n[nt] = ((const float*)(smem + F_OFF_W3V))[n];
  }
  for (int t = wave; t < 14; t += 8) {
    const int r  = t * 16 + lrow;
    const int bb = (r * 9363) >> 18;
    const int p  = r - bb * 28;
    const unsigned pr8 = c_pair[p];
    const int mi = bb * 8 + (int)(pr8 >> 3);
    const int mj = 64 + bb * 8 + (int)(pr8 & 7);
    v4f acc2[4] = {vzero, vzero, vzero, vzero};
#pragma unroll
    for (int ks = 0; ks < 4; ++ks) {
      const int kb = (ks * 32 + lko) * 2;
      const u32x4 va = *(const u32x4*)(smem + F_OFF_SB + mi * 256 + (kb ^ ((mi & 7) << 4)));
      const u32x4 vb = *(const u32x4*)(smem + F_OFF_SB + mj * 256 + (kb ^ ((mj & 7) << 4)));
      const u32x4 vg = *(const u32x4*)(smem + F_OFF_A  + bb * 256 + (kb ^ ((bb & 7) << 4)));
      u32x4 a2;
#pragma unroll
      for (int w = 0; w < 4; ++w) {
        const float lo = fmaxf(lo2f(va[w]) + lo2f(vb[w]) + lo2f(vg[w]), 0.0f);
        const float hi = fmaxf(hi2f(va[w]) + hi2f(vb[w]) + hi2f(vg[w]), 0.0f);
        a2[w] = pkt(lo, hi);
      }
      union { u32x4 u; bf16x8 h; } cv; cv.u = a2;
#pragma unroll
      for (int nt = 0; nt < 4; ++nt) {
        const int c = nt * 16 + lrow;
        const bf16x8 w2fr = *(const bf16x8*)(smem + F_OFF_W2 + c * 256 + (kb ^ ((c & 7) << 4)));
        acc2[nt] = __builtin_amdgcn_mfma_f32_16x16x32_bf16(cv.h, w2fr, acc2[nt], 0, 0, 0);
      }
    }
    float part[4] = {0.f, 0.f, 0.f, 0.f};
#pragma unroll
    for (int nt = 0; nt < 4; ++nt)
#pragma unroll
      for (int rg = 0; rg < 4; ++rg)
        part[rg] += fmaxf(acc2[nt][rg] + b2n[nt], 0.0f) * w3n[nt];
#pragma unroll
    for (int mk = 1; mk < 16; mk <<= 1)
#pragma unroll
      for (int rg = 0; rg < 4; ++rg) part[rg] += __shfl_xor(part[rg], mk, 16);
    if ((lane & 15) == 0) {
      const int rb = t * 16 + (lane >> 4) * 4;
#pragma unroll
      for (int rg = 0; rg < 4; ++rg) {
        const int rr = rb + rg;
        const int b2_ = (rr * 9363) >> 18;
        const int p2  = rr - b2_ * 28;
        const size_t o = (size_t)(bb0 + b2_) * 28 + p2;
        outp[o] = dmask[o] ? (part[rg] + bias3) : -1.0e9f;
      }
    }
  }
}

extern "C" void kernel_launch(void* const* d_in, const int* in_sizes, int n_in,
                              void* d_out, int out_size, void* d_ws, size_t ws_size,
                              hipStream_t stream) {
  (void)in_sizes; (void)n_in; (void)out_size;
  const float* node = (const float*)d_in[0];
  const float* glob = (const float*)d_in[1];
  const int* dmsk   = (const int*)d_in[3];   // bool -> int32 on upload
  const float* W1 = (const float*)d_in[5];
  const float* b1 = (const float*)d_in[6];
  const float* W2 = (const float*)d_in[7];
  const float* b2 = (const float*)d_in[8];
  const float* W3 = (const float*)d_in[9];
  const float* b3 = (const float*)d_in[10];
  float* outp = (float*)d_out;

  if (ws_size >= (size_t)WS_NEED) {
    char* ws = (char*)d_ws;
    prep_weights<<<28, 1024, 0, stream>>>(W1, W2, ws);
    prep_gp<<<128, 256, 0, stream>>>(glob, b1, ws);
    docking_main<<<2048, 512, 0, stream>>>(node, dmsk, b2, W3, b3, ws, outp);
  } else {
    docking_fused<<<16384 / F_NB, F_THREADS, 0, stream>>>(node, glob, dmsk, W1, b1, W2, b2, W3, b3, outp);
  }
}

// Round 11
// 81.113 us; speedup vs baseline: 1.6887x; 1.0036x over previous
//
#include <hip/hip_runtime.h>

typedef float    v4f    __attribute__((ext_vector_type(4)));
typedef __fp16   f16x8  __attribute__((ext_vector_type(8)));
typedef __fp16   f16x2  __attribute__((ext_vector_type(2)));
typedef short    bf16x8 __attribute__((ext_vector_type(8)));
typedef unsigned u32x4  __attribute__((ext_vector_type(4)));
typedef unsigned short u16;

__constant__ unsigned char c_pair[28] = {
  1,2,3,4,5,6,7, 10,11,12,13,14,15, 19,20,21,22,23, 28,29,30,31, 37,38,39, 46,47, 55
};

static __device__ __forceinline__ unsigned asu(float f){ union{float f;unsigned u;}v; v.f=f; return v.u; }
static __device__ __forceinline__ float lo2f(unsigned d){ union{unsigned u;float f;}v; v.u = d<<16; return v.f; }
static __device__ __forceinline__ float hi2f(unsigned d){ union{unsigned u;float f;}v; v.u = d & 0xffff0000u; return v.f; }
// bf16 pack (fallback kernel only)
static __device__ __forceinline__ unsigned pkt(float lo, float hi){
  return __builtin_amdgcn_perm(asu(hi), asu(lo), 0x07060302u);
}
// f16 pack: one v_cvt_pkrtz_f16_f32
static __device__ __forceinline__ unsigned pkh(float lo, float hi){
  union { f16x2 h; unsigned u; } v;
  v.h = __builtin_amdgcn_cvt_pkrtz(lo, hi);
  return v.u;
}

// ---------------- ws image layout (all f16, 2B elems) ----
#define WS_W1AB 0
#define WS_W1G  65536
#define WS_W2   98304
#define WS_GP   114688
#define WS_NEED 4308992

// ================= prep kernels =================
__global__ __launch_bounds__(1024)
void prep_weights(const float* __restrict__ W1, const float* __restrict__ W2, char* __restrict__ ws)
{
  const int idx = blockIdx.x * 1024 + threadIdx.x;   // 28 blocks * 1024 = 28672
  if (idx < 16384) {
    const int c = idx >> 6, kp = idx & 63;
    const int part = c >> 7, cc = c & 127;
    const float a  = W1[(size_t)(part * 128 + 2 * kp) * 128 + cc];
    const float b_ = W1[(size_t)(part * 128 + 2 * kp + 1) * 128 + cc];
    *(unsigned*)(ws + WS_W1AB + (size_t)c * 256 + ((kp * 4) ^ ((c & 7) << 4))) = pkh(a, b_);
  } else if (idx < 24576) {
    const int j = idx - 16384, c = j >> 6, kp = j & 63;
    const float a  = W1[(size_t)(256 + 2 * kp) * 128 + c];
    const float b_ = W1[(size_t)(256 + 2 * kp + 1) * 128 + c];
    *(unsigned*)(ws + WS_W1G + (size_t)c * 256 + ((kp * 4) ^ ((c & 7) << 4))) = pkh(a, b_);
  } else if (idx < 28672) {
    const int j = idx - 24576, c = j >> 6, kp = j & 63;
    const float a  = W2[(size_t)(2 * kp) * 64 + c];
    const float b_ = W2[(size_t)(2 * kp + 1) * 64 + c];
    *(unsigned*)(ws + WS_W2 + (size_t)c * 256 + ((kp * 4) ^ ((c & 7) << 4))) = pkh(a, b_);
  }
}

__global__ __launch_bounds__(256)
void prep_gp(const float* __restrict__ glob, const float* __restrict__ b1, char* __restrict__ ws)
{
  __shared__ __align__(16) char sm[65536];   // [0,32K) glob tile f16 swz; [32K,64K) W1gT
  const int tid = threadIdx.x;
  const int bb0 = blockIdx.x * 128;          // 128 blocks x 128 batches
  for (int i = tid; i < 2048; i += 256) {
    const u32x4 v = *(const u32x4*)(ws + WS_W1G + i * 16);
    *(u32x4*)(sm + 32768 + i * 16) = v;
  }
  for (int i = tid; i < 4096; i += 256) {
    const int r = i >> 5, q = i & 31;
    const float4 f = *(const float4*)(glob + (size_t)(bb0 + r) * 128 + q * 4);
    int2 w; w.x = (int)pkh(f.x, f.y); w.y = (int)pkh(f.z, f.w);
    *(int2*)(sm + r * 256 + ((q * 8) ^ ((r & 7) << 4))) = w;
  }
  __syncthreads();
  const int wave = tid >> 6, lane = tid & 63, lrow = lane & 15, lko = (lane >> 4) * 8;
  float b1c[8];
#pragma unroll
  for (int nt = 0; nt < 8; ++nt) b1c[nt] = b1[nt * 16 + lrow];
  const v4f vzero = {0.f, 0.f, 0.f, 0.f};
  v4f acc[2][8];
#pragma unroll
  for (int mt = 0; mt < 2; ++mt)
#pragma unroll
    for (int nt = 0; nt < 8; ++nt) acc[mt][nt] = vzero;
#pragma unroll
  for (int ks = 0; ks < 4; ++ks) {
    const int kb = (ks * 32 + lko) * 2;
    f16x8 af[2];
#pragma unroll
    for (int mt = 0; mt < 2; ++mt) {
      const int r = wave * 32 + mt * 16 + lrow;
      af[mt] = *(const f16x8*)(sm + r * 256 + (kb ^ ((r & 7) << 4)));
    }
#pragma unroll
    for (int nt = 0; nt < 8; ++nt) {
      const int c = nt * 16 + lrow;
      const f16x8 bfr = *(const f16x8*)(sm + 32768 + c * 256 + (kb ^ ((c & 7) << 4)));
#pragma unroll
      for (int mt = 0; mt < 2; ++mt)
        acc[mt][nt] = __builtin_amdgcn_mfma_f32_16x16x32_f16(af[mt], bfr, acc[mt][nt], 0, 0, 0);
    }
  }
#pragma unroll
  for (int mt = 0; mt < 2; ++mt)
#pragma unroll
    for (int nt = 0; nt < 8; ++nt) {
      const int c = nt * 16 + lrow;
#pragma unroll
      for (int rg = 0; rg < 4; ++rg) {
        const int m = wave * 32 + mt * 16 + (lane >> 4) * 4 + rg;
        const int batch = bb0 + m;
        const int g = batch >> 4, q = m & 15;
        *(u16*)(ws + WS_GP + (size_t)g * 4096 + q * 256 + ((c * 2) ^ ((q & 7) << 4))) =
            (u16)pkh(acc[mt][nt][rg] + b1c[nt], 0.0f);
      }
    }
}

// ================= main kernel =================
// 2048 blocks x 512 threads (8 waves); each block = ONE 8-batch tile (64 node rows).
// LDS = Pa(16K) + Pb'(16K) + W2T(16K) + gp f32(4K) = 52 KiB -> 3 blocks/CU.
// All matrix data f16: phase-2 h1 = elementwise_max(Pa+Pb', 0) via v_pk_*_f16.
#define M2_PA   0        // 16384: Pa  [64 rows][256B swz]
#define M2_PB   16384    // 16384: Pb' [64 rows][256B swz]  (pb + gp + b1)
#define M2_W2   32768    // 16384: W2T rows 0..63
#define M2_GP   49152    // 4096 : gp f32 [8][128]
#define M2_SMEM 53248

__global__ __launch_bounds__(512)
void docking_main(const float* __restrict__ node, const int* __restrict__ dmask,
                  const float* __restrict__ b2, const float* __restrict__ W3,
                  const float* __restrict__ b3,
                  const char* __restrict__ ws, float* __restrict__ outp)
{
  __shared__ __align__(16) char smem[M2_SMEM];
  const int tid = threadIdx.x;
  const int wave = tid >> 6, lane = tid & 63, lrow = lane & 15, lko = (lane >> 4) * 8;
  const int wm = wave >> 2, wn = wave & 3;       // 2 (M-halves of 32 rows) x 4 (N)
  const int bb0 = blockIdx.x * 8;
  const float bias3 = *b3;
  const v4f vzero = {0.f, 0.f, 0.f, 0.f};

  // ---- stage W2T (16B copies) + gp tile (f16 -> f32 unpack) ----
#pragma unroll
  for (int i = 0; i < 2; ++i) {
    const int j = tid + i * 512;
    const u32x4 v = *(const u32x4*)(ws + WS_W2 + j * 16);
    *(u32x4*)(smem + M2_W2 + j * 16) = v;
  }
  {
    const int q = tid >> 6, cp = tid & 63;                     // 8 rows x 64 u32
    const int qq = (bb0 & 15) + q;
    union { unsigned u; f16x2 h; } cv;
    cv.u = *(const unsigned*)(ws + WS_GP + ((size_t)(bb0 >> 4)) * 4096
                              + qq * 256 + ((cp * 4) ^ ((qq & 7) << 4)));
    float* gq = (float*)(smem + M2_GP) + q * 128;
    gq[cp * 2] = (float)cv.h[0]; gq[cp * 2 + 1] = (float)cv.h[1];
  }
  // epilogue constants
  float b2n[4], w3n[4];
#pragma unroll
  for (int nt = 0; nt < 4; ++nt) {
    const int n = nt * 16 + lrow;
    b2n[nt] = b2[n]; w3n[nt] = W3[n];
  }
  __syncthreads();                                   // (A) W2T + gp visible

  // ---- phase 1: proj GEMM  M=64 N=256 K=128; A from global, B via L2 ----
  const char* wsW = ws + WS_W1AB;
  const int pbase = (wn >= 2) ? M2_PB : M2_PA;
  const int rgb = (lane >> 4) * 4;
  const float* aBase = node + ((size_t)bb0 * 8 + (size_t)wm * 32 + lrow) * 128 + lko;
  const float* sgp = (const float*)(smem + M2_GP);

  for (int mt = 0; mt < 2; ++mt) {
    const float* arow = aBase + mt * 16 * 128;
    v4f acc[4] = {vzero, vzero, vzero, vzero};
#pragma unroll
    for (int ks = 0; ks < 4; ++ks) {
      const float* s = arow + ks * 32;
      const float4 f0 = *(const float4*)(s);
      const float4 f1 = *(const float4*)(s + 4);
      union { u32x4 u; f16x8 h; } cv;
      cv.u[0] = pkh(f0.x, f0.y); cv.u[1] = pkh(f0.z, f0.w);
      cv.u[2] = pkh(f1.x, f1.y); cv.u[3] = pkh(f1.z, f1.w);
      const int kb = (ks * 32 + lko) * 2;
#pragma unroll
      for (int nt = 0; nt < 4; ++nt) {
        const int c = wn * 64 + nt * 16 + lrow;
        const f16x8 bfr = *(const f16x8*)(wsW + c * 256 + (kb ^ ((c & 7) << 4)));
        acc[nt] = __builtin_amdgcn_mfma_f32_16x16x32_f16(cv.h, bfr, acc[nt], 0, 0, 0);
      }
    }
    // write proj; Pb waves fold gp (+b1) in
#pragma unroll
    for (int nt = 0; nt < 4; ++nt) {
      const int c = (wn & 1) * 64 + nt * 16 + lrow;
#pragma unroll
      for (int rg = 0; rg < 4; ++rg) {
        const int m = wm * 32 + mt * 16 + rgb + rg;
        float v = acc[nt][rg];
        if (wn >= 2) v += sgp[(m >> 3) * 128 + c];
        *(u16*)(smem + pbase + m * 256 + ((c * 2) ^ ((m & 7) << 4))) =
            (u16)pkh(v, 0.0f);
      }
    }
  }
  __syncthreads();                                   // (B) Pa/Pb' visible

  // ---- phase 2: pair MLP (14 tiles of 16 pair-rows over 8 waves) ----
  for (int t = wave; t < 14; t += 8) {
    const int r  = t * 16 + lrow;                    // 0..223
    const int bb = (r * 9363) >> 18;                 // r/28 for r<2340
    const int p  = r - bb * 28;
    const unsigned pr8 = c_pair[p];
    const int mi = bb * 8 + (int)(pr8 >> 3);
    const int mj = bb * 8 + (int)(pr8 & 7);

    v4f acc2[4] = {vzero, vzero, vzero, vzero};
#pragma unroll
    for (int ks = 0; ks < 4; ++ks) {
      const int kb = (ks * 32 + lko) * 2;
      const f16x8 va = *(const f16x8*)(smem + M2_PA + mi * 256 + (kb ^ ((mi & 7) << 4)));
      const f16x8 vb = *(const f16x8*)(smem + M2_PB + mj * 256 + (kb ^ ((mj & 7) << 4)));
      f16x8 h1 = va + vb;                                        // 4x v_pk_add_f16
      h1 = __builtin_elementwise_max(h1, (f16x8)(__fp16)0.0f);   // 4x v_pk_max_f16
#pragma unroll
      for (int nt = 0; nt < 4; ++nt) {
        const int cc = nt * 16 + lrow;
        const f16x8 w2fr = *(const f16x8*)(smem + M2_W2 + cc * 256 + (kb ^ ((cc & 7) << 4)));
        acc2[nt] = __builtin_amdgcn_mfma_f32_16x16x32_f16(h1, w2fr, acc2[nt], 0, 0, 0);
      }
    }
    float part[4] = {0.f, 0.f, 0.f, 0.f};
#pragma unroll
    for (int nt = 0; nt < 4; ++nt)
#pragma unroll
      for (int rg = 0; rg < 4; ++rg)
        part[rg] += fmaxf(acc2[nt][rg] + b2n[nt], 0.0f) * w3n[nt];
#pragma unroll
    for (int mk = 1; mk < 16; mk <<= 1)
#pragma unroll
      for (int rg = 0; rg < 4; ++rg) part[rg] += __shfl_xor(part[rg], mk, 16);

    if ((lane & 15) == 0) {
      const int rb = t * 16 + (lane >> 4) * 4;
#pragma unroll
      for (int rg = 0; rg < 4; ++rg) {
        const int rr = rb + rg;
        const int b2_ = (rr * 9363) >> 18;
        const int p2  = rr - b2_ * 28;
        const size_t o = (size_t)(bb0 + b2_) * 28 + p2;
        outp[o] = dmask[o] ? (part[rg] + bias3) : -1.0e9f;
      }
    }
  }
}

// ================= fallback (proven R3 fused kernel, bf16) =================
#define F_THREADS 512
#define F_NB      8
#define F_OFF_A    0
#define F_OFF_GL   16384
#define F_OFF_SB   20480
#define F_OFF_W2   53248
#define F_OFF_B1V  69632
#define F_OFF_B2V  70144
#define F_OFF_W3V  70400
#define F_SMEM     70656

__global__ __launch_bounds__(F_THREADS, 4)
void docking_fused(const float* __restrict__ node, const float* __restrict__ glob,
                   const int* __restrict__ dmask,
                   const float* __restrict__ W1, const float* __restrict__ b1,
                   const float* __restrict__ W2, const float* __restrict__ b2,
                   const float* __restrict__ W3, const float* __restrict__ b3,
                   float* __restrict__ outp)
{
  __shared__ __align__(16) char smem[F_SMEM];
  const int tid = threadIdx.x;
  const int bb0 = blockIdx.x * F_NB;
  const size_t nrow0 = (size_t)bb0 * 8;
  const float bias3 = *b3;

  if (tid < 128)      ((float*)(smem + F_OFF_B1V))[tid]       = b1[tid];
  else if (tid < 192) ((float*)(smem + F_OFF_B2V))[tid - 128] = b2[tid - 128];
  else if (tid < 256) ((float*)(smem + F_OFF_W3V))[tid - 192] = W3[tid - 192];

  for (int idx = tid; idx < 64 * 32; idx += F_THREADS) {
    const int r = idx >> 5, q = idx & 31;
    const float4 f = *(const float4*)(node + (nrow0 + (size_t)r) * 128 + q * 4);
    int2 w; w.x = (int)pkt(f.x, f.y); w.y = (int)pkt(f.z, f.w);
    *(int2*)(smem + F_OFF_A + r * 256 + ((q * 8) ^ ((r & 7) << 4))) = w;
  }
  for (int idx = tid; idx < 16 * 32; idx += F_THREADS) {
    const int r = idx >> 5, q = idx & 31;
    float4 f = make_float4(0.f, 0.f, 0.f, 0.f);
    if (r < F_NB) f = *(const float4*)(glob + (size_t)(bb0 + r) * 128 + q * 4);
    int2 w; w.x = (int)pkt(f.x, f.y); w.y = (int)pkt(f.z, f.w);
    *(int2*)(smem + F_OFF_GL + r * 256 + ((q * 8) ^ ((r & 7) << 4))) = w;
  }
  for (int idx = tid; idx < 4096; idx += F_THREADS) {
    const int cl = idx & 7, kl = (idx >> 3) & 7, ch = (idx >> 6) & 7, kh = idx >> 9;
    const int c = cl | (ch << 3), kp = kl | (kh << 3);
    const float a  = W2[(size_t)(2 * kp) * 64 + c];
    const float b_ = W2[(size_t)(2 * kp + 1) * 64 + c];
    *(unsigned*)(smem + F_OFF_W2 + c * 256 + ((kp * 4) ^ ((c & 7) << 4))) = pkt(a, b_);
  }
  auto stageB = [&](int rowOff) {
    for (int idx = tid; idx < 8192; idx += F_THREADS) {
      const int cl = idx & 7, kl = (idx >> 3) & 7, ch = (idx >> 6) & 15, kh = idx >> 10;
      const int c = cl | (ch << 3), kp = kl | (kh << 3);
      const float a  = W1[(size_t)(rowOff + 2 * kp) * 128 + c];
      const float b_ = W1[(size_t)(rowOff + 2 * kp + 1) * 128 + c];
      *(unsigned*)(smem + F_OFF_SB + c * 256 + ((kp * 4) ^ ((c & 7) << 4))) = pkt(a, b_);
    }
  };
  stageB(0);
  __syncthreads();

  const int wave = tid >> 6, lane = tid & 63;
  const int lrow = lane & 15;
  const int lko  = (lane >> 4) * 8;
  const int wmt = wave >> 1, wnh = wave & 1;
  const v4f vzero = {0.f, 0.f, 0.f, 0.f};

  bf16x8 af[4];
#pragma unroll
  for (int ks = 0; ks < 4; ++ks) {
    const int r = wmt * 16 + lrow;
    af[ks] = *(const bf16x8*)(smem + F_OFF_A + r * 256 + (((ks * 32 + lko) * 2) ^ ((r & 7) << 4)));
  }
  v4f acc_a[4] = {vzero, vzero, vzero, vzero};
#pragma unroll
  for (int ks = 0; ks < 4; ++ks) {
    const int kb = (ks * 32 + lko) * 2;
#pragma unroll
    for (int nt = 0; nt < 4; ++nt) {
      const int c = wnh * 64 + nt * 16 + lrow;
      const bf16x8 bfr = *(const bf16x8*)(smem + F_OFF_SB + c * 256 + (kb ^ ((c & 7) << 4)));
      acc_a[nt] = __builtin_amdgcn_mfma_f32_16x16x32_bf16(af[ks], bfr, acc_a[nt], 0, 0, 0);
    }
  }
  __syncthreads();
  stageB(128);
  __syncthreads();
  v4f acc_b[4] = {vzero, vzero, vzero, vzero};
#pragma unroll
  for (int ks = 0; ks < 4; ++ks) {
    const int kb = (ks * 32 + lko) * 2;
#pragma unroll
    for (int nt = 0; nt < 4; ++nt) {
      const int c = wnh * 64 + nt * 16 + lrow;
      const bf16x8 bfr = *(const bf16x8*)(smem + F_OFF_SB + c * 256 + (kb ^ ((c & 7) << 4)));
      acc_b[nt] = __builtin_amdgcn_mfma_f32_16x16x32_bf16(af[ks], bfr, acc_b[nt], 0, 0, 0);
    }
  }
  __syncthreads();
  stageB(256);
  __syncthreads();
  v4f accg = vzero;
#pragma unroll
  for (int ks = 0; ks < 4; ++ks) {
    const int kb = (ks * 32 + lko) * 2;
    const bf16x8 ag = *(const bf16x8*)(smem + F_OFF_GL + lrow * 256 + (kb ^ ((lrow & 7) << 4)));
    const int cg = wave * 16 + lrow;
    const bf16x8 bg = *(const bf16x8*)(smem + F_OFF_SB + cg * 256 + (kb ^ ((cg & 7) << 4)));
    accg = __builtin_amdgcn_mfma_f32_16x16x32_bf16(ag, bg, accg, 0, 0, 0);
  }
  __syncthreads();
  {
    const int rgb = (lane >> 4) * 4;
#pragma unroll
    for (int nt = 0; nt < 4; ++nt) {
      const int c = wnh * 64 + nt * 16 + lrow;
#pragma unroll
      for (int rg = 0; rg < 4; ++rg) {
        const int m = wmt * 16 + rgb + rg;
        const int sw = (c * 2) ^ ((m & 7) << 4);
        *(u16*)(smem + F_OFF_SB + m * 256 + sw)        = (u16)(asu(acc_a[nt][rg]) >> 16);
        *(u16*)(smem + F_OFF_SB + (64 + m) * 256 + sw) = (u16)(asu(acc_b[nt][rg]) >> 16);
      }
    }
    const int cg = wave * 16 + lrow;
    const float b1c = ((const float*)(smem + F_OFF_B1V))[cg];
#pragma unroll
    for (int rg = 0; rg < 4; ++rg) {
      const int bbr = rgb + rg;
      if (bbr < F_NB)
        *(u16*)(smem + F_OFF_A + bbr * 256 + ((cg * 2) ^ ((bbr & 7) << 4))) =
            (u16)(asu(accg[rg] + b1c) >> 16);
    }
  }
  __syncthreads();

  float b2n[4], w3n[4];
#pragma unroll
  for (int nt = 0; nt < 4; ++nt) {
    const int n = nt * 16 + lrow;
    b2n[nt] = ((const float*)(smem + F_OFF_B2V))[n];
    w3n[nt] = ((const float*)(smem + F_OFF_W3V))[n];
  }
  for (int t = wave; t < 14; t += 8) {
    const int r  = t * 16 + lrow;
    const int bb = (r * 9363) >> 18;
    const int p  = r - bb * 28;
    const unsigned pr8 = c_pair[p];
    const int mi = bb * 8 + (int)(pr8 >> 3);
    const int mj = 64 + bb * 8 + (int)(pr8 & 7);
    v4f acc2[4] = {vzero, vzero, vzero, vzero};
#pragma unroll
    for (int ks = 0; ks < 4; ++ks) {
      const int kb = (ks * 32 + lko) * 2;
      const u32x4 va = *(const u32x4*)(smem + F_OFF_SB + mi * 256 + (kb ^ ((mi & 7) << 4)));
      const u32x4 vb = *(const u32x4*)(smem + F_OFF_SB + mj * 256 + (kb ^ ((mj & 7) << 4)));
      const u32x4 vg = *(const u32x4*)(smem + F_OFF_A  + bb * 256 + (kb ^ ((bb & 7) << 4)));
      u32x4 a2;
#pragma unroll
      for (int w = 0; w < 4; ++w) {
        const float lo = fmaxf(lo2f(va[w]) + lo2f(vb[w]) + lo2f(vg[w]), 0.0f);
        const float hi = fmaxf(hi2f(va[w]) + hi2f(vb[w]) + hi2f(vg[w]), 0.0f);
        a2[w] = pkt(lo, hi);
      }
      union { u32x4 u; bf16x8 h; } cv; cv.u = a2;
#pragma unroll
      for (int nt = 0; nt < 4; ++nt) {
        const int c = nt * 16 + lrow;
        const bf16x8 w2fr = *(const bf16x8*)(smem + F_OFF_W2 + c * 256 + (kb ^ ((c & 7) << 4)));
        acc2[nt] = __builtin_amdgcn_mfma_f32_16x16x32_bf16(cv.h, w2fr, acc2[nt], 0, 0, 0);
      }
    }
    float part[4] = {0.f, 0.f, 0.f, 0.f};
#pragma unroll
    for (int nt = 0; nt < 4; ++nt)
#pragma unroll
      for (int rg = 0; rg < 4; ++rg)
        part[rg] += fmaxf(acc2[nt][rg] + b2n[nt], 0.0f) * w3n[nt];
#pragma unroll
    for (int mk = 1; mk < 16; mk <<= 1)
#pragma unroll
      for (int rg = 0; rg < 4; ++rg) part[rg] += __shfl_xor(part[rg], mk, 16);
    if ((lane & 15) == 0) {
      const int rb = t * 16 + (lane >> 4) * 4;
#pragma unroll
      for (int rg = 0; rg < 4; ++rg) {
        const int rr = rb + rg;
        const int b2_ = (rr * 9363) >> 18;
        const int p2  = rr - b2_ * 28;
        const size_t o = (size_t)(bb0 + b2_) * 28 + p2;
        outp[o] = dmask[o] ? (part[rg] + bias3) : -1.0e9f;
      }
    }
  }
}

extern "C" void kernel_launch(void* const* d_in, const int* in_sizes, int n_in,
                              void* d_out, int out_size, void* d_ws, size_t ws_size,
                              hipStream_t stream) {
  (void)in_sizes; (void)n_in; (void)out_size;
  const float* node = (const float*)d_in[0];
  const float* glob = (const float*)d_in[1];
  const int* dmsk   = (const int*)d_in[3];   // bool -> int32 on upload
  const float* W1 = (const float*)d_in[5];
  const float* b1 = (const float*)d_in[6];
  const float* W2 = (const float*)d_in[7];
  const float* b2 = (const float*)d_in[8];
  const float* W3 = (const float*)d_in[9];
  const float* b3 = (const float*)d_in[10];
  float* outp = (float*)d_out;

  if (ws_size >= (size_t)WS_NEED) {
    char* ws = (char*)d_ws;
    prep_weights<<<28, 1024, 0, stream>>>(W1, W2, ws);
    prep_gp<<<128, 256, 0, stream>>>(glob, b1, ws);
    docking_main<<<2048, 512, 0, stream>>>(node, dmsk, b2, W3, b3, ws, outp);
  } else {
    docking_fused<<<16384 / F_NB, F_THREADS, 0, stream>>>(node, glob, dmsk, W1, b1, W2, b2, W3, b3, outp);
  }
}

// Round 12
// 64.359 us; speedup vs baseline: 2.1283x; 1.2603x over previous
//
#include <hip/hip_runtime.h>

typedef float    v4f    __attribute__((ext_vector_type(4)));
typedef __fp16   f16x8  __attribute__((ext_vector_type(8)));
typedef __fp16   f16x2  __attribute__((ext_vector_type(2)));
typedef short    bf16x8 __attribute__((ext_vector_type(8)));
typedef unsigned u32x4  __attribute__((ext_vector_type(4)));
typedef unsigned short u16;

__constant__ unsigned char c_pair[28] = {
  1,2,3,4,5,6,7, 10,11,12,13,14,15, 19,20,21,22,23, 28,29,30,31, 37,38,39, 46,47, 55
};

static __device__ __forceinline__ unsigned asu(float f){ union{float f;unsigned u;}v; v.f=f; return v.u; }
static __device__ __forceinline__ float lo2f(unsigned d){ union{unsigned u;float f;}v; v.u = d<<16; return v.f; }
static __device__ __forceinline__ float hi2f(unsigned d){ union{unsigned u;float f;}v; v.u = d & 0xffff0000u; return v.f; }
// bf16 pack (fallback kernel only)
static __device__ __forceinline__ unsigned pkt(float lo, float hi){
  return __builtin_amdgcn_perm(asu(hi), asu(lo), 0x07060302u);
}
// f16 pack: one v_cvt_pkrtz_f16_f32
static __device__ __forceinline__ unsigned pkh(float lo, float hi){
  union { f16x2 h; unsigned u; } v;
  v.h = __builtin_amdgcn_cvt_pkrtz(lo, hi);
  return v.u;
}

// ---------------- ws image layout (all f16, 2B elems) ----
#define WS_W1AB 0
#define WS_W1G  65536
#define WS_W2   98304
#define WS_GP   114688
#define WS_NEED 4308992

// ================= prep kernels =================
__global__ __launch_bounds__(1024)
void prep_weights(const float* __restrict__ W1, const float* __restrict__ W2, char* __restrict__ ws)
{
  const int idx = blockIdx.x * 1024 + threadIdx.x;   // 28 blocks * 1024 = 28672
  if (idx < 16384) {
    const int c = idx >> 6, kp = idx & 63;
    const int part = c >> 7, cc = c & 127;
    const float a  = W1[(size_t)(part * 128 + 2 * kp) * 128 + cc];
    const float b_ = W1[(size_t)(part * 128 + 2 * kp + 1) * 128 + cc];
    *(unsigned*)(ws + WS_W1AB + (size_t)c * 256 + ((kp * 4) ^ ((c & 7) << 4))) = pkh(a, b_);
  } else if (idx < 24576) {
    const int j = idx - 16384, c = j >> 6, kp = j & 63;
    const float a  = W1[(size_t)(256 + 2 * kp) * 128 + c];
    const float b_ = W1[(size_t)(256 + 2 * kp + 1) * 128 + c];
    *(unsigned*)(ws + WS_W1G + (size_t)c * 256 + ((kp * 4) ^ ((c & 7) << 4))) = pkh(a, b_);
  } else if (idx < 28672) {
    const int j = idx - 24576, c = j >> 6, kp = j & 63;
    const float a  = W2[(size_t)(2 * kp) * 64 + c];
    const float b_ = W2[(size_t)(2 * kp + 1) * 64 + c];
    *(unsigned*)(ws + WS_W2 + (size_t)c * 256 + ((kp * 4) ^ ((c & 7) << 4))) = pkh(a, b_);
  }
}

__global__ __launch_bounds__(256)
void prep_gp(const float* __restrict__ glob, const float* __restrict__ b1, char* __restrict__ ws)
{
  __shared__ __align__(16) char sm[65536];   // [0,32K) glob tile f16 swz; [32K,64K) W1gT
  const int tid = threadIdx.x;
  const int bb0 = blockIdx.x * 128;          // 128 blocks x 128 batches
  for (int i = tid; i < 2048; i += 256) {
    const u32x4 v = *(const u32x4*)(ws + WS_W1G + i * 16);
    *(u32x4*)(sm + 32768 + i * 16) = v;
  }
  for (int i = tid; i < 4096; i += 256) {
    const int r = i >> 5, q = i & 31;
    const float4 f = *(const float4*)(glob + (size_t)(bb0 + r) * 128 + q * 4);
    int2 w; w.x = (int)pkh(f.x, f.y); w.y = (int)pkh(f.z, f.w);
    *(int2*)(sm + r * 256 + ((q * 8) ^ ((r & 7) << 4))) = w;
  }
  __syncthreads();
  const int wave = tid >> 6, lane = tid & 63, lrow = lane & 15, lko = (lane >> 4) * 8;
  float b1c[8];
#pragma unroll
  for (int nt = 0; nt < 8; ++nt) b1c[nt] = b1[nt * 16 + lrow];
  const v4f vzero = {0.f, 0.f, 0.f, 0.f};
  v4f acc[2][8];
#pragma unroll
  for (int mt = 0; mt < 2; ++mt)
#pragma unroll
    for (int nt = 0; nt < 8; ++nt) acc[mt][nt] = vzero;
#pragma unroll
  for (int ks = 0; ks < 4; ++ks) {
    const int kb = (ks * 32 + lko) * 2;
    f16x8 af[2];
#pragma unroll
    for (int mt = 0; mt < 2; ++mt) {
      const int r = wave * 32 + mt * 16 + lrow;
      af[mt] = *(const f16x8*)(sm + r * 256 + (kb ^ ((r & 7) << 4)));
    }
#pragma unroll
    for (int nt = 0; nt < 8; ++nt) {
      const int c = nt * 16 + lrow;
      const f16x8 bfr = *(const f16x8*)(sm + 32768 + c * 256 + (kb ^ ((c & 7) << 4)));
#pragma unroll
      for (int mt = 0; mt < 2; ++mt)
        acc[mt][nt] = __builtin_amdgcn_mfma_f32_16x16x32_f16(af[mt], bfr, acc[mt][nt], 0, 0, 0);
    }
  }
#pragma unroll
  for (int mt = 0; mt < 2; ++mt)
#pragma unroll
    for (int nt = 0; nt < 8; ++nt) {
      const int c = nt * 16 + lrow;
#pragma unroll
      for (int rg = 0; rg < 4; ++rg) {
        const int m = wave * 32 + mt * 16 + (lane >> 4) * 4 + rg;
        const int batch = bb0 + m;
        const int g = batch >> 4, q = m & 15;
        *(u16*)(ws + WS_GP + (size_t)g * 4096 + q * 256 + ((c * 2) ^ ((q & 7) << 4))) =
            (u16)pkh(acc[mt][nt][rg] + b1c[nt], 0.0f);
      }
    }
}

// ================= main kernel =================
// 2048 blocks x 512 threads (8 waves); each block = ONE 8-batch tile (64 node rows).
// LDS = Pa(16K) + Pb'(16K) + ND(16K: node f16 staged, reused for W2T) + gp(4K) + V(512)
//     = 53760 B -> 3 blocks/CU.
// Phase 1: A-frags via LDS (coalesced global stage), B hoisted per-ks (shared by both mt).
#define M3_PA   0
#define M3_PB   16384
#define M3_ND   32768    // node f16 swz in phase 1; W2T in phase 2
#define M3_GP   49152
#define M3_V    53248    // b2 f32[64] | W3 f32[64]
#define M3_SMEM 53760

__global__ __launch_bounds__(512)
void docking_main(const float* __restrict__ node, const int* __restrict__ dmask,
                  const float* __restrict__ b2, const float* __restrict__ W3,
                  const float* __restrict__ b3,
                  const char* __restrict__ ws, float* __restrict__ outp)
{
  __shared__ __align__(16) char smem[M3_SMEM];
  const int tid = threadIdx.x;
  const int wave = tid >> 6, lane = tid & 63, lrow = lane & 15, lko = (lane >> 4) * 8;
  const int wm = wave >> 2, wn = wave & 3;       // 2 (M-halves of 32 rows) x 4 (N)
  const int bb0 = blockIdx.x * 8;
  const float bias3 = *b3;
  const v4f vzero = {0.f, 0.f, 0.f, 0.f};

  // ---- stage node tile (COALESCED: consecutive lanes read consecutive float4) ----
  for (int idx = tid; idx < 64 * 32; idx += 512) {       // 4 iters
    const int r = idx >> 5, q = idx & 31;
    const float4 f = *(const float4*)(node + ((size_t)bb0 * 8 + r) * 128 + q * 4);
    int2 w; w.x = (int)pkh(f.x, f.y); w.y = (int)pkh(f.z, f.w);
    *(int2*)(smem + M3_ND + r * 256 + ((q * 8) ^ ((r & 7) << 4))) = w;
  }
  // ---- stage gp tile (f16 -> f32) + b2/W3 ----
  {
    const int q = tid >> 6, cp = tid & 63;               // 8 rows x 64 u32
    const int qq = (bb0 & 15) + q;
    union { unsigned u; f16x2 h; } cv;
    cv.u = *(const unsigned*)(ws + WS_GP + ((size_t)(bb0 >> 4)) * 4096
                              + qq * 256 + ((cp * 4) ^ ((qq & 7) << 4)));
    float* gq = (float*)(smem + M3_GP) + q * 128;
    gq[cp * 2] = (float)cv.h[0]; gq[cp * 2 + 1] = (float)cv.h[1];
  }
  if (tid < 64)       ((float*)(smem + M3_V))[tid] = b2[tid];
  else if (tid < 128) ((float*)(smem + M3_V))[tid] = W3[tid - 64];
  __syncthreads();                                   // (A) node + gp + consts visible

  // ---- phase 1: proj GEMM M=64 N=256 K=128; A from LDS, B hoisted per-ks from L2 ----
  const char* wsW = ws + WS_W1AB;
  const int pbase = (wn >= 2) ? M3_PB : M3_PA;
  const int rgb = (lane >> 4) * 4;
  const float* sgp = (const float*)(smem + M3_GP);

  v4f acc[2][4];
#pragma unroll
  for (int mt = 0; mt < 2; ++mt)
#pragma unroll
    for (int nt = 0; nt < 4; ++nt) acc[mt][nt] = vzero;

#pragma unroll
  for (int ks = 0; ks < 4; ++ks) {
    const int kb = (ks * 32 + lko) * 2;
    f16x8 Bf[4];
#pragma unroll
    for (int nt = 0; nt < 4; ++nt) {
      const int c = wn * 64 + nt * 16 + lrow;
      Bf[nt] = *(const f16x8*)(wsW + c * 256 + (kb ^ ((c & 7) << 4)));
    }
#pragma unroll
    for (int mt = 0; mt < 2; ++mt) {
      const int rr = wm * 32 + mt * 16 + lrow;
      const f16x8 Af = *(const f16x8*)(smem + M3_ND + rr * 256 + (kb ^ ((rr & 7) << 4)));
#pragma unroll
      for (int nt = 0; nt < 4; ++nt)
        acc[mt][nt] = __builtin_amdgcn_mfma_f32_16x16x32_f16(Af, Bf[nt], acc[mt][nt], 0, 0, 0);
    }
  }
  // proj writes (Pb waves fold gp)
#pragma unroll
  for (int mt = 0; mt < 2; ++mt)
#pragma unroll
    for (int nt = 0; nt < 4; ++nt) {
      const int c = (wn & 1) * 64 + nt * 16 + lrow;
#pragma unroll
      for (int rg = 0; rg < 4; ++rg) {
        const int m = wm * 32 + mt * 16 + rgb + rg;
        float v = acc[mt][nt][rg];
        if (wn >= 2) v += sgp[(m >> 3) * 128 + c];
        *(u16*)(smem + pbase + m * 256 + ((c * 2) ^ ((m & 7) << 4))) =
            (u16)pkh(v, 0.0f);
      }
    }
  __syncthreads();                                   // (B1) all node reads done

  // ---- stage W2T over the dead node buffer ----
#pragma unroll
  for (int i = 0; i < 2; ++i) {
    const int j = tid + i * 512;
    const u32x4 v = *(const u32x4*)(ws + WS_W2 + j * 16);
    *(u32x4*)(smem + M3_ND + j * 16) = v;
  }
  __syncthreads();                                   // (B2) W2T + Pa/Pb' visible

  // ---- phase 2: pair MLP (14 tiles of 16 pair-rows over 8 waves) ----
  const float* sV = (const float*)(smem + M3_V);
  for (int t = wave; t < 14; t += 8) {
    const int r  = t * 16 + lrow;                    // 0..223
    const int bb = (r * 9363) >> 18;                 // r/28 for r<2340
    const int p  = r - bb * 28;
    const unsigned pr8 = c_pair[p];
    const int mi = bb * 8 + (int)(pr8 >> 3);
    const int mj = bb * 8 + (int)(pr8 & 7);

    v4f acc2[4] = {vzero, vzero, vzero, vzero};
#pragma unroll
    for (int ks = 0; ks < 4; ++ks) {
      const int kb = (ks * 32 + lko) * 2;
      const f16x8 va = *(const f16x8*)(smem + M3_PA + mi * 256 + (kb ^ ((mi & 7) << 4)));
      const f16x8 vb = *(const f16x8*)(smem + M3_PB + mj * 256 + (kb ^ ((mj & 7) << 4)));
      f16x8 h1 = va + vb;                                        // v_pk_add_f16
      h1 = __builtin_elementwise_max(h1, (f16x8)(__fp16)0.0f);   // v_pk_max_f16
#pragma unroll
      for (int nt = 0; nt < 4; ++nt) {
        const int cc = nt * 16 + lrow;
        const f16x8 w2fr = *(const f16x8*)(smem + M3_ND + cc * 256 + (kb ^ ((cc & 7) << 4)));
        acc2[nt] = __builtin_amdgcn_mfma_f32_16x16x32_f16(h1, w2fr, acc2[nt], 0, 0, 0);
      }
    }
    float part[4] = {0.f, 0.f, 0.f, 0.f};
#pragma unroll
    for (int nt = 0; nt < 4; ++nt) {
      const int n = nt * 16 + lrow;
      const float b2v = sV[n], w3v = sV[64 + n];
#pragma unroll
      for (int rg = 0; rg < 4; ++rg)
        part[rg] += fmaxf(acc2[nt][rg] + b2v, 0.0f) * w3v;
    }
#pragma unroll
    for (int mk = 1; mk < 16; mk <<= 1)
#pragma unroll
      for (int rg = 0; rg < 4; ++rg) part[rg] += __shfl_xor(part[rg], mk, 16);

    if ((lane & 15) == 0) {
      const int rb = t * 16 + (lane >> 4) * 4;
#pragma unroll
      for (int rg = 0; rg < 4; ++rg) {
        const int rr = rb + rg;
        const int b2_ = (rr * 9363) >> 18;
        const int p2  = rr - b2_ * 28;
        const size_t o = (size_t)(bb0 + b2_) * 28 + p2;
        outp[o] = dmask[o] ? (part[rg] + bias3) : -1.0e9f;
      }
    }
  }
}

// ================= fallback (proven R3 fused kernel, bf16) =================
#define F_THREADS 512
#define F_NB      8
#define F_OFF_A    0
#define F_OFF_GL   16384
#define F_OFF_SB   20480
#define F_OFF_W2   53248
#define F_OFF_B1V  69632
#define F_OFF_B2V  70144
#define F_OFF_W3V  70400
#define F_SMEM     70656

__global__ __launch_bounds__(F_THREADS, 4)
void docking_fused(const float* __restrict__ node, const float* __restrict__ glob,
                   const int* __restrict__ dmask,
                   const float* __restrict__ W1, const float* __restrict__ b1,
                   const float* __restrict__ W2, const float* __restrict__ b2,
                   const float* __restrict__ W3, const float* __restrict__ b3,
                   float* __restrict__ outp)
{
  __shared__ __align__(16) char smem[F_SMEM];
  const int tid = threadIdx.x;
  const int bb0 = blockIdx.x * F_NB;
  const size_t nrow0 = (size_t)bb0 * 8;
  const float bias3 = *b3;

  if (tid < 128)      ((float*)(smem + F_OFF_B1V))[tid]       = b1[tid];
  else if (tid < 192) ((float*)(smem + F_OFF_B2V))[tid - 128] = b2[tid - 128];
  else if (tid < 256) ((float*)(smem + F_OFF_W3V))[tid - 192] = W3[tid - 192];

  for (int idx = tid; idx < 64 * 32; idx += F_THREADS) {
    const int r = idx >> 5, q = idx & 31;
    const float4 f = *(const float4*)(node + (nrow0 + (size_t)r) * 128 + q * 4);
    int2 w; w.x = (int)pkt(f.x, f.y); w.y = (int)pkt(f.z, f.w);
    *(int2*)(smem + F_OFF_A + r * 256 + ((q * 8) ^ ((r & 7) << 4))) = w;
  }
  for (int idx = tid; idx < 16 * 32; idx += F_THREADS) {
    const int r = idx >> 5, q = idx & 31;
    float4 f = make_float4(0.f, 0.f, 0.f, 0.f);
    if (r < F_NB) f = *(const float4*)(glob + (size_t)(bb0 + r) * 128 + q * 4);
    int2 w; w.x = (int)pkt(f.x, f.y); w.y = (int)pkt(f.z, f.w);
    *(int2*)(smem + F_OFF_GL + r * 256 + ((q * 8) ^ ((r & 7) << 4))) = w;
  }
  for (int idx = tid; idx < 4096; idx += F_THREADS) {
    const int cl = idx & 7, kl = (idx >> 3) & 7, ch = (idx >> 6) & 7, kh = idx >> 9;
    const int c = cl | (ch << 3), kp = kl | (kh << 3);
    const float a  = W2[(size_t)(2 * kp) * 64 + c];
    const float b_ = W2[(size_t)(2 * kp + 1) * 64 + c];
    *(unsigned*)(smem + F_OFF_W2 + c * 256 + ((kp * 4) ^ ((c & 7) << 4))) = pkt(a, b_);
  }
  auto stageB = [&](int rowOff) {
    for (int idx = tid; idx < 8192; idx += F_THREADS) {
      const int cl = idx & 7, kl = (idx >> 3) & 7, ch = (idx >> 6) & 15, kh = idx >> 10;
      const int c = cl | (ch << 3), kp = kl | (kh << 3);
      const float a  = W1[(size_t)(rowOff + 2 * kp) * 128 + c];
      const float b_ = W1[(size_t)(rowOff + 2 * kp + 1) * 128 + c];
      *(unsigned*)(smem + F_OFF_SB + c * 256 + ((kp * 4) ^ ((c & 7) << 4))) = pkt(a, b_);
    }
  };
  stageB(0);
  __syncthreads();

  const int wave = tid >> 6, lane = tid & 63;
  const int lrow = lane & 15;
  const int lko  = (lane >> 4) * 8;
  const int wmt = wave >> 1, wnh = wave & 1;
  const v4f vzero = {0.f, 0.f, 0.f, 0.f};

  bf16x8 af[4];
#pragma unroll
  for (int ks = 0; ks < 4; ++ks) {
    const int r = wmt * 16 + lrow;
    af[ks] = *(const bf16x8*)(smem + F_OFF_A + r * 256 + (((ks * 32 + lko) * 2) ^ ((r & 7) << 4)));
  }
  v4f acc_a[4] = {vzero, vzero, vzero, vzero};
#pragma unroll
  for (int ks = 0; ks < 4; ++ks) {
    const int kb = (ks * 32 + lko) * 2;
#pragma unroll
    for (int nt = 0; nt < 4; ++nt) {
      const int c = wnh * 64 + nt * 16 + lrow;
      const bf16x8 bfr = *(const bf16x8*)(smem + F_OFF_SB + c * 256 + (kb ^ ((c & 7) << 4)));
      acc_a[nt] = __builtin_amdgcn_mfma_f32_16x16x32_bf16(af[ks], bfr, acc_a[nt], 0, 0, 0);
    }
  }
  __syncthreads();
  stageB(128);
  __syncthreads();
  v4f acc_b[4] = {vzero, vzero, vzero, vzero};
#pragma unroll
  for (int ks = 0; ks < 4; ++ks) {
    const int kb = (ks * 32 + lko) * 2;
#pragma unroll
    for (int nt = 0; nt < 4; ++nt) {
      const int c = wnh * 64 + nt * 16 + lrow;
      const bf16x8 bfr = *(const bf16x8*)(smem + F_OFF_SB + c * 256 + (kb ^ ((c & 7) << 4)));
      acc_b[nt] = __builtin_amdgcn_mfma_f32_16x16x32_bf16(af[ks], bfr, acc_b[nt], 0, 0, 0);
    }
  }
  __syncthreads();
  stageB(256);
  __syncthreads();
  v4f accg = vzero;
#pragma unroll
  for (int ks = 0; ks < 4; ++ks) {
    const int kb = (ks * 32 + lko) * 2;
    const bf16x8 ag = *(const bf16x8*)(smem + F_OFF_GL + lrow * 256 + (kb ^ ((lrow & 7) << 4)));
    const int cg = wave * 16 + lrow;
    const bf16x8 bg = *(const bf16x8*)(smem + F_OFF_SB + cg * 256 + (kb ^ ((cg & 7) << 4)));
    accg = __builtin_amdgcn_mfma_f32_16x16x32_bf16(ag, bg, accg, 0, 0, 0);
  }
  __syncthreads();
  {
    const int rgb = (lane >> 4) * 4;
#pragma unroll
    for (int nt = 0; nt < 4; ++nt) {
      const int c = wnh * 64 + nt * 16 + lrow;
#pragma unroll
      for (int rg = 0; rg < 4; ++rg) {
        const int m = wmt * 16 + rgb + rg;
        const int sw = (c * 2) ^ ((m & 7) << 4);
        *(u16*)(smem + F_OFF_SB + m * 256 + sw)        = (u16)(asu(acc_a[nt][rg]) >> 16);
        *(u16*)(smem + F_OFF_SB + (64 + m) * 256 + sw) = (u16)(asu(acc_b[nt][rg]) >> 16);
      }
    }
    const int cg = wave * 16 + lrow;
    const float b1c = ((const float*)(smem + F_OFF_B1V))[cg];
#pragma unroll
    for (int rg = 0; rg < 4; ++rg) {
      const int bbr = rgb + rg;
      if (bbr < F_NB)
        *(u16*)(smem + F_OFF_A + bbr * 256 + ((cg * 2) ^ ((bbr & 7) << 4))) =
            (u16)(asu(accg[rg] + b1c) >> 16);
    }
  }
  __syncthreads();

  float b2n[4], w3n[4];
#pragma unroll
  for (int nt = 0; nt < 4; ++nt) {
    const int n = nt * 16 + lrow;
    b2n[nt] = ((const float*)(smem + F_OFF_B2V))[n];
    w3n[nt] = ((const float*)(smem + F_OFF_W3V))[n];
  }
  for (int t = wave; t < 14; t += 8) {
    const int r  = t * 16 + lrow;
    const int bb = (r * 9363) >> 18;
    const int p  = r - bb * 28;
    const unsigned pr8 = c_pair[p];
    const int mi = bb * 8 + (int)(pr8 >> 3);
    const int mj = 64 + bb * 8 + (int)(pr8 & 7);
    v4f acc2[4] = {vzero, vzero, vzero, vzero};
#pragma unroll
    for (int ks = 0; ks < 4; ++ks) {
      const int kb = (ks * 32 + lko) * 2;
      const u32x4 va = *(const u32x4*)(smem + F_OFF_SB + mi * 256 + (kb ^ ((mi & 7) << 4)));
      const u32x4 vb = *(const u32x4*)(smem + F_OFF_SB + mj * 256 + (kb ^ ((mj & 7) << 4)));
      const u32x4 vg = *(const u32x4*)(smem + F_OFF_A  + bb * 256 + (kb ^ ((bb & 7) << 4)));
      u32x4 a2;
#pragma unroll
      for (int w = 0; w < 4; ++w) {
        const float lo = fmaxf(lo2f(va[w]) + lo2f(vb[w]) + lo2f(vg[w]), 0.0f);
        const float hi = fmaxf(hi2f(va[w]) + hi2f(vb[w]) + hi2f(vg[w]), 0.0f);
        a2[w] = pkt(lo, hi);
      }
      union { u32x4 u; bf16x8 h; } cv; cv.u = a2;
#pragma unroll
      for (int nt = 0; nt < 4; ++nt) {
        const int c = nt * 16 + lrow;
        const bf16x8 w2fr = *(const bf16x8*)(smem + F_OFF_W2 + c * 256 + (kb ^ ((c & 7) << 4)));
        acc2[nt] = __builtin_amdgcn_mfma_f32_16x16x32_bf16(cv.h, w2fr, acc2[nt], 0, 0, 0);
      }
    }
    float part[4] = {0.f, 0.f, 0.f, 0.f};
#pragma unroll
    for (int nt = 0; nt < 4; ++nt)
#pragma unroll
      for (int rg = 0; rg < 4; ++rg)
        part[rg] += fmaxf(acc2[nt][rg] + b2n[nt], 0.0f) * w3n[nt];
#pragma unroll
    for (int mk = 1; mk < 16; mk <<= 1)
#pragma unroll
      for (int rg = 0; rg < 4; ++rg) part[rg] += __shfl_xor(part[rg], mk, 16);
    if ((lane & 15) == 0) {
      const int rb = t * 16 + (lane >> 4) * 4;
#pragma unroll
      for (int rg = 0; rg < 4; ++rg) {
        const int rr = rb + rg;
        const int b2_ = (rr * 9363) >> 18;
        const int p2  = rr - b2_ * 28;
        const size_t o = (size_t)(bb0 + b2_) * 28 + p2;
        outp[o] = dmask[o] ? (part[rg] + bias3) : -1.0e9f;
      }
    }
  }
}

extern "C" void kernel_launch(void* const* d_in, const int* in_sizes, int n_in,
                              void* d_out, int out_size, void* d_ws, size_t ws_size,
                              hipStream_t stream) {
  (void)in_sizes; (void)n_in; (void)out_size;
  const float* node = (const float*)d_in[0];
  const float* glob = (const float*)d_in[1];
  const int* dmsk   = (const int*)d_in[3];   // bool -> int32 on upload
  const float* W1 = (const float*)d_in[5];
  const float* b1 = (const float*)d_in[6];
  const float* W2 = (const float*)d_in[7];
  const float* b2 = (const float*)d_in[8];
  const float* W3 = (const float*)d_in[9];
  const float* b3 = (const float*)d_in[10];
  float* outp = (float*)d_out;

  if (ws_size >= (size_t)WS_NEED) {
    char* ws = (char*)d_ws;
    prep_weights<<<28, 1024, 0, stream>>>(W1, W2, ws);
    prep_gp<<<128, 256, 0, stream>>>(glob, b1, ws);
    docking_main<<<2048, 512, 0, stream>>>(node, dmsk, b2, W3, b3, ws, outp);
  } else {
    docking_fused<<<16384 / F_NB, F_THREADS, 0, stream>>>(node, glob, dmsk, W1, b1, W2, b2, W3, b3, outp);
  }
}